// Round 8
// baseline (224.741 us; speedup 1.0000x reference)
//
#include <hip/hip_runtime.h>
#include <hip/hip_bf16.h>

#define EPSF 1e-8f
#define NN 50000
#define DD 128
#define BB 64
#define LL 512
#define PP0 200000
#define PP1 50000
#define SCALE 0.08838834764831845f  // 1/sqrt(128)

// edge grid topology: G0B edge0-blocks + G1B edge1-blocks, sliced across
// the three sequential mega-kernels (proj/attn/head).
#define G0B 1024
#define G1B 640
#define EK2 416   // edge blocks riding with proj
#define EK3 896   // edge blocks riding with attn
#define EK4 352   // edge blocks riding with head

typedef float f4v __attribute__((ext_vector_type(4)));
typedef short s8v __attribute__((ext_vector_type(8)));
typedef short s4v __attribute__((ext_vector_type(4)));

__device__ __forceinline__ float logsigf(float x) {
    float s = 1.f / (1.f + __expf(-x));
    return __logf(s + EPSF);
}

__device__ __forceinline__ float red64(float v) {
    #pragma unroll
    for (int m = 32; m >= 1; m >>= 1) v += __shfl_xor(v, m, 64);
    return v;
}
__device__ __forceinline__ float red16(float v) {
    #pragma unroll
    for (int m = 8; m >= 1; m >>= 1) v += __shfl_xor(v, m, 64);
    return v;
}
__device__ __forceinline__ float red8(float v) {
    #pragma unroll
    for (int m = 4; m >= 1; m >>= 1) v += __shfl_xor(v, m, 64);
    return v;
}

__device__ __forceinline__ void block_atomic_sum(float local, float* dst) {
    local = red64(local);
    __shared__ float w4[4];
    if ((threadIdx.x & 63) == 0) w4[threadIdx.x >> 6] = local;
    __syncthreads();
    if (threadIdx.x == 0) atomicAdd(dst, w4[0] + w4[1] + w4[2] + w4[3]);
}

// float -> bf16 bits (round-to-nearest-even)
__device__ __forceinline__ unsigned short f2bf(float f) {
    unsigned u = __float_as_uint(f);
    unsigned r = (u + 0x7fffu + ((u >> 16) & 1u)) >> 16;
    return (unsigned short)r;
}
__device__ __forceinline__ float bf2f(unsigned short u) {
    return __uint_as_float(((unsigned)u) << 16);
}

__device__ __forceinline__ float dot8bf(s8v a, s8v b) {
    float s = 0.f;
    #pragma unroll
    for (int j = 0; j < 8; j++)
        s += bf2f((unsigned short)a[j]) * bf2f((unsigned short)b[j]);
    return s;
}

// ---------------- edge slice (device fn, shared by the 3 mega-kernels) ------
// eid in [0, G0B+G1B): [0,G0B) = edge0 role, [G0B,..) = edge1 role.
__device__ void edge_slice(int eid, const unsigned short* __restrict__ emb16,
                           const int* __restrict__ pos, const int* __restrict__ neg,
                           const int* __restrict__ pos1, const int* __restrict__ neg1,
                           float* __restrict__ acc)
{
    if (eid < G0B) {
        // 8 lanes per pair: 8 independent chains/wave, 3-step reduce
        int sub = threadIdx.x & 7;
        int g0 = eid * 32 + (threadIdx.x >> 3);
        const int ng = G0B * 32;
        float local = 0.f;
        for (int grp = g0; grp < 2 * PP0; grp += ng) {
            bool isneg = grp >= PP0;
            const int* e = isneg ? (neg + 2 * (grp - PP0)) : (pos + 2 * grp);
            int h = e[0], t = e[1];
            const unsigned short* hr = emb16 + (size_t)h * DD + 16 * sub;
            const unsigned short* tr = emb16 + (size_t)t * DD + 16 * sub;
            s8v a0 = *(const s8v*)&hr[0];
            s8v a1 = *(const s8v*)&hr[8];
            s8v b0 = *(const s8v*)&tr[0];
            s8v b1 = *(const s8v*)&tr[8];
            float d = red8(dot8bf(a0, b0) + dot8bf(a1, b1));
            if (sub == 0) local += logsigf(isneg ? -d : d);
        }
        block_atomic_sum(local, acc);
    } else {
        int sub = threadIdx.x & 15;
        int g0 = (eid - G0B) * 16 + (threadIdx.x >> 4);
        const int ng = G1B * 16;
        float local = 0.f;
        for (int i = g0; i < PP1; i += ng) {
            int ph = pos1[2 * i], pt = pos1[2 * i + 1];
            s8v vph = *(const s8v*)&emb16[(size_t)ph * DD + 8 * sub];
            s8v vpt = *(const s8v*)&emb16[(size_t)pt * DD + 8 * sub];
            float ps = red16(dot8bf(vph, vpt));
            #pragma unroll
            for (int mloop = 0; mloop < 4; mloop++) {
                int g = mloop * PP1 + i;
                int nh = neg1[2 * g], nt = neg1[2 * g + 1];
                s8v vnh = *(const s8v*)&emb16[(size_t)nh * DD + 8 * sub];
                s8v vnt = *(const s8v*)&emb16[(size_t)nt * DD + 8 * sub];
                float sh = red16(dot8bf(vnh, vpt));
                float st = red16(dot8bf(vph, vnt));
                if (sub == 0) local += logsigf(ps - sh) + logsigf(ps - st);
            }
        }
        block_atomic_sum(local, acc + 1);
    }
}

// ---------------- one-shot convert ------------------------------------------
__global__ __launch_bounds__(256) void cvt_emb_kernel(
    const float* __restrict__ emb, unsigned short* __restrict__ emb16)
{
    int stride = gridDim.x * 256 * 8;
    for (int i = (blockIdx.x * 256 + threadIdx.x) * 8; i < NN * DD; i += stride) {
        float4 a = *(const float4*)&emb[i];
        float4 b = *(const float4*)&emb[i + 4];
        s8v o;
        o[0] = (short)f2bf(a.x); o[1] = (short)f2bf(a.y);
        o[2] = (short)f2bf(a.z); o[3] = (short)f2bf(a.w);
        o[4] = (short)f2bf(b.x); o[5] = (short)f2bf(b.y);
        o[6] = (short)f2bf(b.z); o[7] = (short)f2bf(b.w);
        *(s8v*)&emb16[i] = o;
    }
}

// ---------------- K2: QKV projection (512 blocks) + edge slice [0,EK2) ------
__global__ __launch_bounds__(256) void proj_edges_kernel(
    const unsigned short* __restrict__ emb16, const float* __restrict__ Wrep,
    const float* __restrict__ Wq, const float* __restrict__ Wk,
    const float* __restrict__ Wv, const int* __restrict__ qseq,
    const int* __restrict__ cseq, unsigned short* __restrict__ QT16,
    unsigned short* __restrict__ KT16, unsigned short* __restrict__ VT16T,
    const int* __restrict__ pos, const int* __restrict__ neg,
    const int* __restrict__ pos1, const int* __restrict__ neg1,
    float* __restrict__ acc)
{
    if (blockIdx.x >= 512) {
        edge_slice(blockIdx.x - 512, emb16, pos, neg, pos1, neg1, acc);
        return;
    }
    int b = blockIdx.x >> 3;
    int t0 = (blockIdx.x & 7) << 6;
    __shared__ unsigned short Itok[64 * 136];
    __shared__ unsigned short Wl[128 * 136];   // also V^T[r][t] stride 72 in epilogue
    __shared__ int qs[64];
    __shared__ int cs[64];
    int tid = threadIdx.x;
    if (tid < 64) {
        qs[tid] = qseq[b * LL + t0 + tid];
        cs[tid] = cseq[b * LL + t0 + tid];
    }
    __syncthreads();
    {   // stage I[t][d] = emb[qs[t]][d] + Wrep[d][cs[t]] as bf16
        int t = tid >> 2, d0 = (tid & 3) * 32;
        const unsigned short* er = emb16 + (size_t)qs[t] * DD + d0;
        int c = cs[t];
        #pragma unroll
        for (int e = 0; e < 32; e += 8) {
            s8v raw = *(const s8v*)&er[e];
            s8v o;
            #pragma unroll
            for (int j = 0; j < 8; j++) {
                float f = bf2f((unsigned short)raw[j]) + Wrep[(d0 + e + j) * 2 + c];
                o[j] = (short)f2bf(f);
            }
            *(s8v*)&Itok[t * 136 + d0 + e] = o;
        }
    }
    int w = tid >> 6, lane = tid & 63, n = lane & 15, quad = lane >> 4;

    for (int w3 = 0; w3 < 3; w3++) {
        const float* Wsel = (w3 == 0) ? Wq : (w3 == 1) ? Wk : Wv;
        __syncthreads();
        {   // stage W[w3]: fp32 global -> bf16 LDS
            const float* src = Wsel + (tid >> 1) * DD + (tid & 1) * 64;
            unsigned short* dst = &Wl[(tid >> 1) * 136 + (tid & 1) * 64];
            #pragma unroll
            for (int e = 0; e < 64; e += 8) {
                float4 x = *(const float4*)&src[e];
                float4 y = *(const float4*)&src[e + 4];
                s8v o;
                o[0] = (short)f2bf(x.x); o[1] = (short)f2bf(x.y);
                o[2] = (short)f2bf(x.z); o[3] = (short)f2bf(x.w);
                o[4] = (short)f2bf(y.x); o[5] = (short)f2bf(y.y);
                o[6] = (short)f2bf(y.z); o[7] = (short)f2bf(y.w);
                *(s8v*)&dst[e] = o;
            }
        }
        __syncthreads();
        f4v a2[2][4];
        #pragma unroll
        for (int mt = 0; mt < 2; mt++)
            #pragma unroll
            for (int nt = 0; nt < 4; nt++) a2[mt][nt] = (f4v){0.f, 0.f, 0.f, 0.f};
        #pragma unroll
        for (int c = 0; c < 4; c++) {
            s8v af0 = *(const s8v*)&Wl[(w * 32 + n) * 136 + c * 32 + quad * 8];
            s8v af1 = *(const s8v*)&Wl[(w * 32 + 16 + n) * 136 + c * 32 + quad * 8];
            #pragma unroll
            for (int nt = 0; nt < 4; nt++) {
                s8v bf = *(const s8v*)&Itok[(nt * 16 + n) * 136 + c * 32 + quad * 8];
                a2[0][nt] = __builtin_amdgcn_mfma_f32_16x16x32_bf16(af0, bf, a2[0][nt], 0, 0, 0);
                a2[1][nt] = __builtin_amdgcn_mfma_f32_16x16x32_bf16(af1, bf, a2[1][nt], 0, 0, 0);
            }
        }
        if (w3 < 2) {
            unsigned short* OUT = (w3 == 0) ? QT16 : KT16;
            #pragma unroll
            for (int mt = 0; mt < 2; mt++)
                #pragma unroll
                for (int nt = 0; nt < 4; nt++) {
                    int t = t0 + nt * 16 + n;
                    int r = w * 32 + mt * 16 + quad * 4;
                    s4v o;
                    #pragma unroll
                    for (int rr = 0; rr < 4; rr++) o[rr] = (short)f2bf(a2[mt][nt][rr]);
                    *(s4v*)&OUT[((size_t)(b * LL) + t) * DD + r] = o;
                }
        } else {
            // V: scatter into LDS [r][t] stride 72, then coalesced b128 store
            __syncthreads();
            #pragma unroll
            for (int mt = 0; mt < 2; mt++)
                #pragma unroll
                for (int nt = 0; nt < 4; nt++) {
                    int tl = nt * 16 + n;
                    int r = w * 32 + mt * 16 + quad * 4;
                    #pragma unroll
                    for (int rr = 0; rr < 4; rr++)
                        Wl[(r + rr) * 72 + tl] = f2bf(a2[mt][nt][rr]);
                }
            __syncthreads();
            int row = tid >> 1, half = tid & 1;
            unsigned short* gdst = VT16T + ((size_t)b * DD + row) * LL + t0 + half * 32;
            const unsigned short* lsrc = &Wl[row * 72 + half * 32];
            #pragma unroll
            for (int e = 0; e < 32; e += 8)
                *(s8v*)&gdst[e] = *(const s8v*)&lsrc[e];
        }
    }
}

// ---------------- K3: flash attention (512 blocks) + edge slice -------------
__global__ __launch_bounds__(256) void attn_edges_kernel(
    const unsigned short* __restrict__ QT16, const unsigned short* __restrict__ KT16,
    const unsigned short* __restrict__ VT16T, float* __restrict__ BvT,
    const unsigned short* __restrict__ emb16,
    const int* __restrict__ pos, const int* __restrict__ neg,
    const int* __restrict__ pos1, const int* __restrict__ neg1,
    float* __restrict__ acc)
{
    if (blockIdx.x >= 512) {
        edge_slice(EK2 + (blockIdx.x - 512), emb16, pos, neg, pos1, neg1, acc);
        return;
    }
    int id = blockIdx.x;
    int r0 = id & 255;
    int b = r0 & 63;
    int qt = (id >> 8) ? (7 - (r0 >> 6)) : (r0 >> 6);

    __shared__ unsigned short K_lds[64 * 136];   // [key][d]
    __shared__ unsigned short Vt_lds[128 * 72];  // [d][key]
    __shared__ unsigned short P_lds[64 * 72];    // [query][key]

    int tid = threadIdx.x;
    int w = tid >> 6;
    int lane = tid & 63;
    int n = lane & 15;
    int quad = lane >> 4;
    int gj = qt * 64 + w * 16 + n;

    s8v qfrag[4];
    {
        const unsigned short* qrow = QT16 + ((size_t)(b * LL) + gj) * DD;
        #pragma unroll
        for (int c = 0; c < 4; c++)
            qfrag[c] = *(const s8v*)&qrow[c * 32 + quad * 8];
    }

    f4v oacc[8];
    #pragma unroll
    for (int dt = 0; dt < 8; dt++) oacc[dt] = (f4v){0.f, 0.f, 0.f, 0.f};
    float m_run = -INFINITY, l_run = 0.f;

    s8v kreg[4], vreg[4];
    #pragma unroll
    for (int rep = 0; rep < 4; rep++) {
        int idx = rep * 2048 + tid * 8;
        int ki = idx >> 7, kd = idx & 127;
        kreg[rep] = *(const s8v*)&KT16[((size_t)(b * LL) + ki) * DD + kd];
        int vr = idx >> 6, vc = idx & 63;
        vreg[rep] = *(const s8v*)&VT16T[((size_t)b * DD + vr) * LL + vc];
    }

    for (int kt = 0; kt <= qt; ++kt) {
        __syncthreads();
        #pragma unroll
        for (int rep = 0; rep < 4; rep++) {
            int idx = rep * 2048 + tid * 8;
            int ki = idx >> 7, kd = idx & 127;
            *(s8v*)&K_lds[ki * 136 + kd] = kreg[rep];
            int vr = idx >> 6, vc = idx & 63;
            *(s8v*)&Vt_lds[vr * 72 + vc] = vreg[rep];
        }
        __syncthreads();
        if (kt < qt) {
            #pragma unroll
            for (int rep = 0; rep < 4; rep++) {
                int idx = rep * 2048 + tid * 8;
                int ki = idx >> 7, kd = idx & 127;
                kreg[rep] = *(const s8v*)&KT16[((size_t)(b * LL) + (kt + 1) * 64 + ki) * DD + kd];
                int vr = idx >> 6, vc = idx & 63;
                vreg[rep] = *(const s8v*)&VT16T[((size_t)b * DD + vr) * LL + (kt + 1) * 64 + vc];
            }
        }

        f4v sacc[4];
        #pragma unroll
        for (int mt = 0; mt < 4; mt++) sacc[mt] = (f4v){0.f, 0.f, 0.f, 0.f};
        #pragma unroll
        for (int c = 0; c < 4; c++) {
            #pragma unroll
            for (int mt = 0; mt < 4; mt++) {
                s8v af = *(const s8v*)&K_lds[(mt * 16 + n) * 136 + c * 32 + quad * 8];
                sacc[mt] = __builtin_amdgcn_mfma_f32_16x16x32_bf16(af, qfrag[c], sacc[mt], 0, 0, 0);
            }
        }

        bool diag = (kt == qt);
        float mloc = -INFINITY;
        #pragma unroll
        for (int mt = 0; mt < 4; mt++) {
            #pragma unroll
            for (int rr = 0; rr < 4; rr++) {
                float s = sacc[mt][rr] * SCALE;
                if (diag && (kt * 64 + mt * 16 + quad * 4 + rr) > gj) s = -INFINITY;
                sacc[mt][rr] = s;
                mloc = fmaxf(mloc, s);
            }
        }
        mloc = fmaxf(mloc, __shfl_xor(mloc, 16));
        mloc = fmaxf(mloc, __shfl_xor(mloc, 32));
        float mnew = fmaxf(m_run, mloc);
        float alpha = __expf(m_run - mnew);
        m_run = mnew;

        float rsum = 0.f;
        #pragma unroll
        for (int mt = 0; mt < 4; mt++) {
            s4v pp;
            #pragma unroll
            for (int rr = 0; rr < 4; rr++) {
                float p = __expf(sacc[mt][rr] - mnew);
                rsum += p;
                pp[rr] = (short)f2bf(p);
            }
            *(s4v*)&P_lds[(w * 16 + n) * 72 + mt * 16 + quad * 4] = pp;
        }
        rsum += __shfl_xor(rsum, 16);
        rsum += __shfl_xor(rsum, 32);
        l_run = l_run * alpha + rsum;

        #pragma unroll
        for (int rr = 0; rr < 4; rr++) {
            float a_r = __shfl(alpha, quad * 4 + rr);
            #pragma unroll
            for (int dt = 0; dt < 8; dt++) oacc[dt][rr] *= a_r;
        }

        #pragma unroll
        for (int cc = 0; cc < 2; cc++) {
            s8v pf = *(const s8v*)&P_lds[(w * 16 + n) * 72 + cc * 32 + quad * 8];
            #pragma unroll
            for (int dt = 0; dt < 8; dt++) {
                s8v vf = *(const s8v*)&Vt_lds[(dt * 16 + n) * 72 + cc * 32 + quad * 8];
                oacc[dt] = __builtin_amdgcn_mfma_f32_16x16x32_bf16(pf, vf, oacc[dt], 0, 0, 0);
            }
        }
    }

    float linv = 1.f / l_run;
    #pragma unroll
    for (int rr = 0; rr < 4; rr++) {
        float li = __shfl(linv, quad * 4 + rr);
        int t = qt * 64 + w * 16 + quad * 4 + rr;
        float* orow = BvT + ((size_t)(b * LL) + t) * DD;
        #pragma unroll
        for (int dt = 0; dt < 8; dt++)
            orow[dt * 16 + n] = oacc[dt][rr] * li;
    }
}

// ---------------- K4: head+pred (512 blocks) + edge slice -------------------
__global__ __launch_bounds__(256) void head_edges_kernel(
    const float* __restrict__ Hd, const float* __restrict__ BvT,
    const unsigned short* __restrict__ emb16, const float* __restrict__ uinit,
    const int* __restrict__ qseq, const int* __restrict__ cseq,
    const int* __restrict__ pos, const int* __restrict__ neg,
    const int* __restrict__ pos1, const int* __restrict__ neg1,
    float* __restrict__ acc)
{
    if (blockIdx.x >= 512) {
        edge_slice(EK2 + EK3 + (blockIdx.x - 512), emb16, pos, neg, pos1, neg1, acc);
        return;
    }
    int b = blockIdx.x >> 3;
    int t0 = (blockIdx.x & 7) << 6;
    __shared__ unsigned short Btok[64 * 136];   // Bv tile; reused for O after MFMA
    __shared__ unsigned short Hl[128 * 136];
    int tid = threadIdx.x;
    {
        int t = tid >> 2, d0 = (tid & 3) * 32;
        const float* br = BvT + ((size_t)(b * LL) + t0 + t) * DD + d0;
        #pragma unroll
        for (int e = 0; e < 32; e += 8) {
            float4 x = *(const float4*)&br[e];
            float4 y = *(const float4*)&br[e + 4];
            s8v o;
            o[0] = (short)f2bf(x.x); o[1] = (short)f2bf(x.y);
            o[2] = (short)f2bf(x.z); o[3] = (short)f2bf(x.w);
            o[4] = (short)f2bf(y.x); o[5] = (short)f2bf(y.y);
            o[6] = (short)f2bf(y.z); o[7] = (short)f2bf(y.w);
            *(s8v*)&Btok[t * 136 + d0 + e] = o;
        }
    }
    {   // Head_agg fp32 -> bf16 LDS
        const float* src = Hd + (tid >> 1) * DD + (tid & 1) * 64;
        unsigned short* dst = &Hl[(tid >> 1) * 136 + (tid & 1) * 64];
        #pragma unroll
        for (int e = 0; e < 64; e += 8) {
            float4 x = *(const float4*)&src[e];
            float4 y = *(const float4*)&src[e + 4];
            s8v o;
            o[0] = (short)f2bf(x.x); o[1] = (short)f2bf(x.y);
            o[2] = (short)f2bf(x.z); o[3] = (short)f2bf(x.w);
            o[4] = (short)f2bf(y.x); o[5] = (short)f2bf(y.y);
            o[6] = (short)f2bf(y.z); o[7] = (short)f2bf(y.w);
            *(s8v*)&dst[e] = o;
        }
    }
    __syncthreads();

    int w = tid >> 6, lane = tid & 63, n = lane & 15, quad = lane >> 4;
    f4v a2[2][4];
    #pragma unroll
    for (int mt = 0; mt < 2; mt++)
        #pragma unroll
        for (int nt = 0; nt < 4; nt++) a2[mt][nt] = (f4v){0.f, 0.f, 0.f, 0.f};
    #pragma unroll
    for (int c = 0; c < 4; c++) {
        s8v af0 = *(const s8v*)&Hl[(w * 32 + n) * 136 + c * 32 + quad * 8];
        s8v af1 = *(const s8v*)&Hl[(w * 32 + 16 + n) * 136 + c * 32 + quad * 8];
        #pragma unroll
        for (int nt = 0; nt < 4; nt++) {
            s8v bf = *(const s8v*)&Btok[(nt * 16 + n) * 136 + c * 32 + quad * 8];
            a2[0][nt] = __builtin_amdgcn_mfma_f32_16x16x32_bf16(af0, bf, a2[0][nt], 0, 0, 0);
            a2[1][nt] = __builtin_amdgcn_mfma_f32_16x16x32_bf16(af1, bf, a2[1][nt], 0, 0, 0);
        }
    }
    __syncthreads();   // everyone done reading Btok; reuse it for O
    #pragma unroll
    for (int mt = 0; mt < 2; mt++)
        #pragma unroll
        for (int nt = 0; nt < 4; nt++) {
            int tl = nt * 16 + n;
            int r = w * 32 + mt * 16 + quad * 4;
            #pragma unroll
            for (int rr = 0; rr < 4; rr++)
                Btok[tl * 136 + r + rr] = f2bf(a2[mt][nt][rr]);
        }
    __syncthreads();

    int g = tid >> 4, sub = tid & 15;
    float local = 0.f;
    #pragma unroll
    for (int tt = 0; tt < 4; tt++) {
        int tl = g * 4 + tt;
        int t = t0 + tl + 1;
        if (t < LL) {
            s8v uv = *(const s8v*)&Btok[tl * 136 + sub * 8];
            int qi = qseq[b * LL + t];
            s8v ev = *(const s8v*)&emb16[(size_t)qi * DD + sub * 8];
            float s = red16(dot8bf(uv, ev));
            if (sub == 0) {
                float c = (float)cseq[b * LL + t];
                float pred = 1.f / (1.f + __expf(-s));
                local += c * __logf(pred + EPSF) + (1.f - c) * __logf(1.f - pred + EPSF);
            }
        }
    }
    if (t0 == 0 && g == 0) {
        int qi = qseq[b * LL];
        s8v ev = *(const s8v*)&emb16[(size_t)qi * DD + sub * 8];
        float4 u0 = *(const float4*)&uinit[sub * 8];
        float4 u1 = *(const float4*)&uinit[sub * 8 + 4];
        float s = u0.x * bf2f((unsigned short)ev[0]) + u0.y * bf2f((unsigned short)ev[1])
                + u0.z * bf2f((unsigned short)ev[2]) + u0.w * bf2f((unsigned short)ev[3])
                + u1.x * bf2f((unsigned short)ev[4]) + u1.y * bf2f((unsigned short)ev[5])
                + u1.z * bf2f((unsigned short)ev[6]) + u1.w * bf2f((unsigned short)ev[7]);
        s = red16(s);
        if (sub == 0) {
            float c = (float)cseq[b * LL];
            float pred = 1.f / (1.f + __expf(-s));
            local += c * __logf(pred + EPSF) + (1.f - c) * __logf(1.f - pred + EPSF);
        }
    }
    block_atomic_sum(local, acc + 2);
}

// ---------------- final combine ---------------------------------------------
__global__ void combine_kernel(
    const float* __restrict__ acc, const float* __restrict__ sd0p,
    const float* __restrict__ sd1p, const float* __restrict__ sdqp,
    float* __restrict__ out)
{
    if (threadIdx.x == 0 && blockIdx.x == 0) {
        float l0 = -acc[0], l1 = -acc[1], ls = -acc[2];
        float s0 = *sd0p, s1 = *sd1p, ss = *sdqp;
        float tf = l0 / (s0 * s0 + EPSF) + 400000.f * logf(s0 + EPSF)
                 + l1 / (s1 * s1 + EPSF) + 400000.f * logf(s1 + EPSF)
                 + ls / (ss * ss + EPSF) + 512.f * logf(ss + EPSF);
        out[0] = tf;
    }
}

extern "C" void kernel_launch(void* const* d_in, const int* in_sizes, int n_in,
                              void* d_out, int out_size, void* d_ws, size_t ws_size,
                              hipStream_t stream) {
    const float* emb   = (const float*)d_in[0];
    const float* Wrep  = (const float*)d_in[1];
    const float* Wq    = (const float*)d_in[2];
    const float* Wk    = (const float*)d_in[3];
    const float* Wv    = (const float*)d_in[4];
    const float* Hd    = (const float*)d_in[5];
    const float* uinit = (const float*)d_in[6];
    const float* sd0   = (const float*)d_in[7];
    const float* sd1   = (const float*)d_in[8];
    const float* sdq   = (const float*)d_in[9];
    const int* pe0 = (const int*)d_in[10];
    const int* ne0 = (const int*)d_in[11];
    const int* pe1 = (const int*)d_in[12];
    const int* ne1 = (const int*)d_in[13];
    const int* qs  = (const int*)d_in[14];
    const int* cs  = (const int*)d_in[15];

    const size_t SZ = (size_t)BB * LL * DD;   // 4,194,304
    char* base = (char*)d_ws;
    float* acc = (float*)base;                                  // 256 B
    unsigned short* emb16 = (unsigned short*)(base + 256);      // 12.8 MB
    unsigned short* QT16  = emb16 + (size_t)NN * DD;
    unsigned short* KT16  = QT16 + SZ;
    unsigned short* VT16T = KT16 + SZ;                          // [b][128][512]
    float* BvT = (float*)(VT16T + SZ);                          // fp32

    hipMemsetAsync(acc, 0, 256, stream);

    cvt_emb_kernel<<<1024, 256, 0, stream>>>(emb, emb16);

    proj_edges_kernel<<<512 + EK2, 256, 0, stream>>>(
        emb16, Wrep, Wq, Wk, Wv, qs, cs, QT16, KT16, VT16T,
        pe0, ne0, pe1, ne1, acc);
    attn_edges_kernel<<<512 + EK3, 256, 0, stream>>>(
        QT16, KT16, VT16T, BvT, emb16, pe0, ne0, pe1, ne1, acc);
    head_edges_kernel<<<512 + EK4, 256, 0, stream>>>(
        Hd, BvT, emb16, uinit, qs, cs, pe0, ne0, pe1, ne1, acc);

    combine_kernel<<<1, 64, 0, stream>>>(acc, sd0, sd1, sdq, (float*)d_out);
}

// Round 9
// 203.122 us; speedup vs baseline: 1.1064x; 1.1064x over previous
//
#include <hip/hip_runtime.h>
#include <hip/hip_bf16.h>

#define EPSF 1e-8f
#define NN 50000
#define DD 128
#define BB 64
#define LL 512
#define PP0 200000
#define PP1 50000
#define SCALE 0.08838834764831845f  // 1/sqrt(128)

#define E0B 1024
#define E1B 640

typedef float f4v __attribute__((ext_vector_type(4)));
typedef short s8v __attribute__((ext_vector_type(8)));
typedef short s4v __attribute__((ext_vector_type(4)));

__device__ __forceinline__ float logsigf(float x) {
    float s = 1.f / (1.f + __expf(-x));
    return __logf(s + EPSF);
}

__device__ __forceinline__ float red64(float v) {
    #pragma unroll
    for (int m = 32; m >= 1; m >>= 1) v += __shfl_xor(v, m, 64);
    return v;
}
__device__ __forceinline__ float red16(float v) {
    #pragma unroll
    for (int m = 8; m >= 1; m >>= 1) v += __shfl_xor(v, m, 64);
    return v;
}
__device__ __forceinline__ float red8(float v) {
    #pragma unroll
    for (int m = 4; m >= 1; m >>= 1) v += __shfl_xor(v, m, 64);
    return v;
}

__device__ __forceinline__ void block_atomic_sum(float local, float* dst) {
    local = red64(local);
    __shared__ float w4[4];
    if ((threadIdx.x & 63) == 0) w4[threadIdx.x >> 6] = local;
    __syncthreads();
    if (threadIdx.x == 0) atomicAdd(dst, w4[0] + w4[1] + w4[2] + w4[3]);
}

// float -> bf16 bits (round-to-nearest-even)
__device__ __forceinline__ unsigned short f2bf(float f) {
    unsigned u = __float_as_uint(f);
    unsigned r = (u + 0x7fffu + ((u >> 16) & 1u)) >> 16;
    return (unsigned short)r;
}
__device__ __forceinline__ float bf2f(unsigned short u) {
    return __uint_as_float(((unsigned)u) << 16);
}

__device__ __forceinline__ float dot8bf(s8v a, s8v b) {
    float s = 0.f;
    #pragma unroll
    for (int j = 0; j < 8; j++)
        s += bf2f((unsigned short)a[j]) * bf2f((unsigned short)b[j]);
    return s;
}

// ---------------- one-shot convert ------------------------------------------
__global__ __launch_bounds__(256) void cvt_emb_kernel(
    const float* __restrict__ emb, unsigned short* __restrict__ emb16)
{
    int stride = gridDim.x * 256 * 8;
    for (int i = (blockIdx.x * 256 + threadIdx.x) * 8; i < NN * DD; i += stride) {
        float4 a = *(const float4*)&emb[i];
        float4 b = *(const float4*)&emb[i + 4];
        s8v o;
        o[0] = (short)f2bf(a.x); o[1] = (short)f2bf(a.y);
        o[2] = (short)f2bf(a.z); o[3] = (short)f2bf(a.w);
        o[4] = (short)f2bf(b.x); o[5] = (short)f2bf(b.y);
        o[6] = (short)f2bf(b.z); o[7] = (short)f2bf(b.w);
        *(s8v*)&emb16[i] = o;
    }
}

// ---------------- Edge tasks: standalone, small LDS, high occupancy ---------
__global__ __launch_bounds__(256) void edges_kernel(
    const unsigned short* __restrict__ emb16, const int* __restrict__ pos,
    const int* __restrict__ neg, const int* __restrict__ pos1,
    const int* __restrict__ neg1, float* __restrict__ acc)
{
    if (blockIdx.x < E0B) {
        int sub = threadIdx.x & 7;
        int g0 = (blockIdx.x * 256 + threadIdx.x) >> 3;
        const int ng = E0B * 32;
        float local = 0.f;
        for (int grp = g0; grp < 2 * PP0; grp += ng) {
            bool isneg = grp >= PP0;
            const int* e = isneg ? (neg + 2 * (grp - PP0)) : (pos + 2 * grp);
            int h = e[0], t = e[1];
            const unsigned short* hr = emb16 + (size_t)h * DD + 16 * sub;
            const unsigned short* tr = emb16 + (size_t)t * DD + 16 * sub;
            s8v a0 = *(const s8v*)&hr[0];
            s8v a1 = *(const s8v*)&hr[8];
            s8v b0 = *(const s8v*)&tr[0];
            s8v b1 = *(const s8v*)&tr[8];
            float d = red8(dot8bf(a0, b0) + dot8bf(a1, b1));
            if (sub == 0) local += logsigf(isneg ? -d : d);
        }
        block_atomic_sum(local, acc);
    } else {
        int sub = threadIdx.x & 15;
        int g0 = ((blockIdx.x - E0B) * 256 + threadIdx.x) >> 4;
        const int ng = E1B * 16;
        float local = 0.f;
        for (int i = g0; i < PP1; i += ng) {
            int ph = pos1[2 * i], pt = pos1[2 * i + 1];
            s8v vph = *(const s8v*)&emb16[(size_t)ph * DD + 8 * sub];
            s8v vpt = *(const s8v*)&emb16[(size_t)pt * DD + 8 * sub];
            float ps = red16(dot8bf(vph, vpt));
            #pragma unroll
            for (int mloop = 0; mloop < 4; mloop++) {
                int g = mloop * PP1 + i;
                int nh = neg1[2 * g], nt = neg1[2 * g + 1];
                s8v vnh = *(const s8v*)&emb16[(size_t)nh * DD + 8 * sub];
                s8v vnt = *(const s8v*)&emb16[(size_t)nt * DD + 8 * sub];
                float sh = red16(dot8bf(vnh, vpt));
                float st = red16(dot8bf(vph, vnt));
                if (sub == 0) local += logsigf(ps - sh) + logsigf(ps - st);
            }
        }
        block_atomic_sum(local, acc + 1);
    }
}

// ---------------- QKV projection, bf16 MFMA, inline W conversion ------------
__global__ __launch_bounds__(256) void proj_kernel(
    const unsigned short* __restrict__ emb16, const float* __restrict__ Wrep,
    const float* __restrict__ Wq, const float* __restrict__ Wk,
    const float* __restrict__ Wv, const int* __restrict__ qseq,
    const int* __restrict__ cseq, unsigned short* __restrict__ QT16,
    unsigned short* __restrict__ KT16, unsigned short* __restrict__ VT16T)
{
    int b = blockIdx.y;
    int t0 = blockIdx.x * 64;
    __shared__ unsigned short Itok[64 * 136];
    __shared__ unsigned short Wl[128 * 136];   // also V^T[r][t] stride 72 in epilogue
    __shared__ int qs[64];
    __shared__ int cs[64];
    int tid = threadIdx.x;
    if (tid < 64) {
        qs[tid] = qseq[b * LL + t0 + tid];
        cs[tid] = cseq[b * LL + t0 + tid];
    }
    __syncthreads();
    {   // stage I[t][d] = emb[qs[t]][d] + Wrep[d][cs[t]] as bf16
        int t = tid >> 2, d0 = (tid & 3) * 32;
        const unsigned short* er = emb16 + (size_t)qs[t] * DD + d0;
        int c = cs[t];
        #pragma unroll
        for (int e = 0; e < 32; e += 8) {
            s8v raw = *(const s8v*)&er[e];
            s8v o;
            #pragma unroll
            for (int j = 0; j < 8; j++) {
                float f = bf2f((unsigned short)raw[j]) + Wrep[(d0 + e + j) * 2 + c];
                o[j] = (short)f2bf(f);
            }
            *(s8v*)&Itok[t * 136 + d0 + e] = o;
        }
    }
    int w = tid >> 6, lane = tid & 63, n = lane & 15, quad = lane >> 4;

    for (int w3 = 0; w3 < 3; w3++) {
        const float* Wsel = (w3 == 0) ? Wq : (w3 == 1) ? Wk : Wv;
        __syncthreads();
        {   // stage W[w3]: fp32 global -> bf16 LDS
            const float* src = Wsel + (tid >> 1) * DD + (tid & 1) * 64;
            unsigned short* dst = &Wl[(tid >> 1) * 136 + (tid & 1) * 64];
            #pragma unroll
            for (int e = 0; e < 64; e += 8) {
                float4 x = *(const float4*)&src[e];
                float4 y = *(const float4*)&src[e + 4];
                s8v o;
                o[0] = (short)f2bf(x.x); o[1] = (short)f2bf(x.y);
                o[2] = (short)f2bf(x.z); o[3] = (short)f2bf(x.w);
                o[4] = (short)f2bf(y.x); o[5] = (short)f2bf(y.y);
                o[6] = (short)f2bf(y.z); o[7] = (short)f2bf(y.w);
                *(s8v*)&dst[e] = o;
            }
        }
        __syncthreads();
        f4v a2[2][4];
        #pragma unroll
        for (int mt = 0; mt < 2; mt++)
            #pragma unroll
            for (int nt = 0; nt < 4; nt++) a2[mt][nt] = (f4v){0.f, 0.f, 0.f, 0.f};
        #pragma unroll
        for (int c = 0; c < 4; c++) {
            s8v af0 = *(const s8v*)&Wl[(w * 32 + n) * 136 + c * 32 + quad * 8];
            s8v af1 = *(const s8v*)&Wl[(w * 32 + 16 + n) * 136 + c * 32 + quad * 8];
            #pragma unroll
            for (int nt = 0; nt < 4; nt++) {
                s8v bf = *(const s8v*)&Itok[(nt * 16 + n) * 136 + c * 32 + quad * 8];
                a2[0][nt] = __builtin_amdgcn_mfma_f32_16x16x32_bf16(af0, bf, a2[0][nt], 0, 0, 0);
                a2[1][nt] = __builtin_amdgcn_mfma_f32_16x16x32_bf16(af1, bf, a2[1][nt], 0, 0, 0);
            }
        }
        if (w3 < 2) {
            unsigned short* OUT = (w3 == 0) ? QT16 : KT16;
            #pragma unroll
            for (int mt = 0; mt < 2; mt++)
                #pragma unroll
                for (int nt = 0; nt < 4; nt++) {
                    int t = t0 + nt * 16 + n;
                    int r = w * 32 + mt * 16 + quad * 4;
                    s4v o;
                    #pragma unroll
                    for (int rr = 0; rr < 4; rr++) o[rr] = (short)f2bf(a2[mt][nt][rr]);
                    *(s4v*)&OUT[((size_t)(b * LL) + t) * DD + r] = o;
                }
        } else {
            __syncthreads();
            #pragma unroll
            for (int mt = 0; mt < 2; mt++)
                #pragma unroll
                for (int nt = 0; nt < 4; nt++) {
                    int tl = nt * 16 + n;
                    int r = w * 32 + mt * 16 + quad * 4;
                    #pragma unroll
                    for (int rr = 0; rr < 4; rr++)
                        Wl[(r + rr) * 72 + tl] = f2bf(a2[mt][nt][rr]);
                }
            __syncthreads();
            int row = tid >> 1, half = tid & 1;
            unsigned short* gdst = VT16T + ((size_t)b * DD + row) * LL + t0 + half * 32;
            const unsigned short* lsrc = &Wl[row * 72 + half * 32];
            #pragma unroll
            for (int e = 0; e < 32; e += 8)
                *(s8v*)&gdst[e] = *(const s8v*)&lsrc[e];
        }
    }
}

// ---------------- Flash attention + head + pred, fully fused ----------------
// LDS union (52 KB, 3 blocks/CU):
//   kt-loop : K[64*136] | Vt[128*72] | P[64*72]
//   epilogue: Bv[64*136] | Hl[64*136] | O[64*136]
__global__ __launch_bounds__(256) void attn_head_kernel(
    const unsigned short* __restrict__ QT16, const unsigned short* __restrict__ KT16,
    const unsigned short* __restrict__ VT16T, const float* __restrict__ Hd,
    const unsigned short* __restrict__ emb16, const float* __restrict__ uinit,
    const int* __restrict__ qseq, const int* __restrict__ cseq,
    float* __restrict__ acc)
{
    __shared__ unsigned short U[26112];
    unsigned short* K_lds  = U;            // 64*136 = 8704
    unsigned short* Vt_lds = U + 8704;     // 128*72 = 9216
    unsigned short* P_lds  = U + 17920;    // 64*72  = 4608 (end 22528)
    unsigned short* Bv_lds = U;            // 64*136
    unsigned short* Hl     = U + 8704;     // 64*136 (end 17408)
    unsigned short* O_lds  = U + 17408;    // 64*136 (end 26112)

    int id = blockIdx.x;
    int r0 = id & 255;
    int b = r0 & 63;
    int qt = (id >> 8) ? (7 - (r0 >> 6)) : (r0 >> 6);

    int tid = threadIdx.x;
    int w = tid >> 6;
    int lane = tid & 63;
    int n = lane & 15;
    int quad = lane >> 4;
    int gj = qt * 64 + w * 16 + n;

    s8v qfrag[4];
    {
        const unsigned short* qrow = QT16 + ((size_t)(b * LL) + gj) * DD;
        #pragma unroll
        for (int c = 0; c < 4; c++)
            qfrag[c] = *(const s8v*)&qrow[c * 32 + quad * 8];
    }

    f4v oacc[8];
    #pragma unroll
    for (int dt = 0; dt < 8; dt++) oacc[dt] = (f4v){0.f, 0.f, 0.f, 0.f};
    float m_run = -INFINITY, l_run = 0.f;

    s8v kreg[4], vreg[4];
    #pragma unroll
    for (int rep = 0; rep < 4; rep++) {
        int idx = rep * 2048 + tid * 8;
        int ki = idx >> 7, kd = idx & 127;
        kreg[rep] = *(const s8v*)&KT16[((size_t)(b * LL) + ki) * DD + kd];
        int vr = idx >> 6, vc = idx & 63;
        vreg[rep] = *(const s8v*)&VT16T[((size_t)b * DD + vr) * LL + vc];
    }

    for (int kt = 0; kt <= qt; ++kt) {
        __syncthreads();
        #pragma unroll
        for (int rep = 0; rep < 4; rep++) {
            int idx = rep * 2048 + tid * 8;
            int ki = idx >> 7, kd = idx & 127;
            *(s8v*)&K_lds[ki * 136 + kd] = kreg[rep];
            int vr = idx >> 6, vc = idx & 63;
            *(s8v*)&Vt_lds[vr * 72 + vc] = vreg[rep];
        }
        __syncthreads();
        if (kt < qt) {
            #pragma unroll
            for (int rep = 0; rep < 4; rep++) {
                int idx = rep * 2048 + tid * 8;
                int ki = idx >> 7, kd = idx & 127;
                kreg[rep] = *(const s8v*)&KT16[((size_t)(b * LL) + (kt + 1) * 64 + ki) * DD + kd];
                int vr = idx >> 6, vc = idx & 63;
                vreg[rep] = *(const s8v*)&VT16T[((size_t)b * DD + vr) * LL + (kt + 1) * 64 + vc];
            }
        }

        f4v sacc[4];
        #pragma unroll
        for (int mt = 0; mt < 4; mt++) sacc[mt] = (f4v){0.f, 0.f, 0.f, 0.f};
        #pragma unroll
        for (int c = 0; c < 4; c++) {
            #pragma unroll
            for (int mt = 0; mt < 4; mt++) {
                s8v af = *(const s8v*)&K_lds[(mt * 16 + n) * 136 + c * 32 + quad * 8];
                sacc[mt] = __builtin_amdgcn_mfma_f32_16x16x32_bf16(af, qfrag[c], sacc[mt], 0, 0, 0);
            }
        }

        bool diag = (kt == qt);
        float mloc = -INFINITY;
        #pragma unroll
        for (int mt = 0; mt < 4; mt++) {
            #pragma unroll
            for (int rr = 0; rr < 4; rr++) {
                float s = sacc[mt][rr] * SCALE;
                if (diag && (kt * 64 + mt * 16 + quad * 4 + rr) > gj) s = -INFINITY;
                sacc[mt][rr] = s;
                mloc = fmaxf(mloc, s);
            }
        }
        mloc = fmaxf(mloc, __shfl_xor(mloc, 16));
        mloc = fmaxf(mloc, __shfl_xor(mloc, 32));
        float mnew = fmaxf(m_run, mloc);
        float alpha = __expf(m_run - mnew);
        m_run = mnew;

        float rsum = 0.f;
        #pragma unroll
        for (int mt = 0; mt < 4; mt++) {
            s4v pp;
            #pragma unroll
            for (int rr = 0; rr < 4; rr++) {
                float p = __expf(sacc[mt][rr] - mnew);
                rsum += p;
                pp[rr] = (short)f2bf(p);
            }
            *(s4v*)&P_lds[(w * 16 + n) * 72 + mt * 16 + quad * 4] = pp;
        }
        rsum += __shfl_xor(rsum, 16);
        rsum += __shfl_xor(rsum, 32);
        l_run = l_run * alpha + rsum;

        #pragma unroll
        for (int rr = 0; rr < 4; rr++) {
            float a_r = __shfl(alpha, quad * 4 + rr);
            #pragma unroll
            for (int dt = 0; dt < 8; dt++) oacc[dt][rr] *= a_r;
        }

        #pragma unroll
        for (int cc = 0; cc < 2; cc++) {
            s8v pf = *(const s8v*)&P_lds[(w * 16 + n) * 72 + cc * 32 + quad * 8];
            #pragma unroll
            for (int dt = 0; dt < 8; dt++) {
                s8v vf = *(const s8v*)&Vt_lds[(dt * 16 + n) * 72 + cc * 32 + quad * 8];
                oacc[dt] = __builtin_amdgcn_mfma_f32_16x16x32_bf16(pf, vf, oacc[dt], 0, 0, 0);
            }
        }
    }

    // ---- epilogue: Bv -> LDS (bf16, /l), O = Head_agg @ Bv, pred loss ----
    __syncthreads();   // all waves done with K/V/P LDS
    {
        float linv = 1.f / l_run;
        #pragma unroll
        for (int rr = 0; rr < 4; rr++) {
            float li = __shfl(linv, quad * 4 + rr);
            int tl = w * 16 + quad * 4 + rr;
            #pragma unroll
            for (int dt = 0; dt < 8; dt++)
                Bv_lds[tl * 136 + dt * 16 + n] = f2bf(oacc[dt][rr] * li);
        }
    }

    #pragma unroll
    for (int pass = 0; pass < 2; pass++) {
        __syncthreads();   // Bv ready / previous pass's Hl reads done
        {   // stage H rows [pass*64, +64) fp32 -> bf16
            int r = tid >> 2, d0 = (tid & 3) * 32;
            const float* src = Hd + (size_t)(pass * 64 + r) * DD + d0;
            #pragma unroll
            for (int e = 0; e < 32; e += 8) {
                float4 x = *(const float4*)&src[e];
                float4 y = *(const float4*)&src[e + 4];
                s8v o;
                o[0] = (short)f2bf(x.x); o[1] = (short)f2bf(x.y);
                o[2] = (short)f2bf(x.z); o[3] = (short)f2bf(x.w);
                o[4] = (short)f2bf(y.x); o[5] = (short)f2bf(y.y);
                o[6] = (short)f2bf(y.z); o[7] = (short)f2bf(y.w);
                *(s8v*)&Hl[r * 136 + d0 + e] = o;
            }
        }
        __syncthreads();
        f4v o2[4];
        #pragma unroll
        for (int nt = 0; nt < 4; nt++) o2[nt] = (f4v){0.f, 0.f, 0.f, 0.f};
        #pragma unroll
        for (int c = 0; c < 4; c++) {
            s8v af = *(const s8v*)&Hl[(w * 16 + n) * 136 + c * 32 + quad * 8];
            #pragma unroll
            for (int nt = 0; nt < 4; nt++) {
                s8v bf = *(const s8v*)&Bv_lds[(nt * 16 + n) * 136 + c * 32 + quad * 8];
                o2[nt] = __builtin_amdgcn_mfma_f32_16x16x32_bf16(af, bf, o2[nt], 0, 0, 0);
            }
        }
        int rbase = pass * 64 + w * 16 + quad * 4;
        #pragma unroll
        for (int nt = 0; nt < 4; nt++) {
            int tl = nt * 16 + n;
            #pragma unroll
            for (int rr = 0; rr < 4; rr++)
                O_lds[tl * 136 + rbase + rr] = f2bf(o2[nt][rr]);
        }
    }
    __syncthreads();

    // pred: term t = qt*64 + tl + 1 uses u = O[tl]; 16 groups x 16 lanes
    int g2 = tid >> 4, sub = tid & 15;
    float local = 0.f;
    #pragma unroll
    for (int tt = 0; tt < 4; tt++) {
        int tl = g2 * 4 + tt;
        int t = qt * 64 + tl + 1;
        if (t < LL) {
            s8v uv = *(const s8v*)&O_lds[tl * 136 + sub * 8];
            int qi = qseq[b * LL + t];
            s8v ev = *(const s8v*)&emb16[(size_t)qi * DD + sub * 8];
            float s = red16(dot8bf(uv, ev));
            if (sub == 0) {
                float c = (float)cseq[b * LL + t];
                float pred = 1.f / (1.f + __expf(-s));
                local += c * __logf(pred + EPSF) + (1.f - c) * __logf(1.f - pred + EPSF);
            }
        }
    }
    if (qt == 0 && g2 == 0) {   // t = 0 term with user_init (fp32)
        int qi = qseq[b * LL];
        s8v ev = *(const s8v*)&emb16[(size_t)qi * DD + sub * 8];
        float4 u0 = *(const float4*)&uinit[sub * 8];
        float4 u1 = *(const float4*)&uinit[sub * 8 + 4];
        float s = u0.x * bf2f((unsigned short)ev[0]) + u0.y * bf2f((unsigned short)ev[1])
                + u0.z * bf2f((unsigned short)ev[2]) + u0.w * bf2f((unsigned short)ev[3])
                + u1.x * bf2f((unsigned short)ev[4]) + u1.y * bf2f((unsigned short)ev[5])
                + u1.z * bf2f((unsigned short)ev[6]) + u1.w * bf2f((unsigned short)ev[7]);
        s = red16(s);
        if (sub == 0) {
            float c = (float)cseq[b * LL];
            float pred = 1.f / (1.f + __expf(-s));
            local += c * __logf(pred + EPSF) + (1.f - c) * __logf(1.f - pred + EPSF);
        }
    }
    block_atomic_sum(local, acc + 2);
}

// ---------------- final combine ---------------------------------------------
__global__ void combine_kernel(
    const float* __restrict__ acc, const float* __restrict__ sd0p,
    const float* __restrict__ sd1p, const float* __restrict__ sdqp,
    float* __restrict__ out)
{
    if (threadIdx.x == 0 && blockIdx.x == 0) {
        float l0 = -acc[0], l1 = -acc[1], ls = -acc[2];
        float s0 = *sd0p, s1 = *sd1p, ss = *sdqp;
        float tf = l0 / (s0 * s0 + EPSF) + 400000.f * logf(s0 + EPSF)
                 + l1 / (s1 * s1 + EPSF) + 400000.f * logf(s1 + EPSF)
                 + ls / (ss * ss + EPSF) + 512.f * logf(ss + EPSF);
        out[0] = tf;
    }
}

extern "C" void kernel_launch(void* const* d_in, const int* in_sizes, int n_in,
                              void* d_out, int out_size, void* d_ws, size_t ws_size,
                              hipStream_t stream) {
    const float* emb   = (const float*)d_in[0];
    const float* Wrep  = (const float*)d_in[1];
    const float* Wq    = (const float*)d_in[2];
    const float* Wk    = (const float*)d_in[3];
    const float* Wv    = (const float*)d_in[4];
    const float* Hd    = (const float*)d_in[5];
    const float* uinit = (const float*)d_in[6];
    const float* sd0   = (const float*)d_in[7];
    const float* sd1   = (const float*)d_in[8];
    const float* sdq   = (const float*)d_in[9];
    const int* pe0 = (const int*)d_in[10];
    const int* ne0 = (const int*)d_in[11];
    const int* pe1 = (const int*)d_in[12];
    const int* ne1 = (const int*)d_in[13];
    const int* qs  = (const int*)d_in[14];
    const int* cs  = (const int*)d_in[15];

    const size_t SZ = (size_t)BB * LL * DD;   // 4,194,304
    char* base = (char*)d_ws;
    float* acc = (float*)base;                                  // 256 B
    unsigned short* emb16 = (unsigned short*)(base + 256);      // 12.8 MB
    unsigned short* QT16  = emb16 + (size_t)NN * DD;
    unsigned short* KT16  = QT16 + SZ;
    unsigned short* VT16T = KT16 + SZ;                          // [b][128][512]

    hipMemsetAsync(acc, 0, 256, stream);

    cvt_emb_kernel<<<1024, 256, 0, stream>>>(emb, emb16);

    edges_kernel<<<E0B + E1B, 256, 0, stream>>>(emb16, pe0, ne0, pe1, ne1, acc);

    proj_kernel<<<dim3(8, 64), 256, 0, stream>>>(emb16, Wrep, Wq, Wk, Wv,
                                                 qs, cs, QT16, KT16, VT16T);
    attn_head_kernel<<<512, 256, 0, stream>>>(QT16, KT16, VT16T, Hd, emb16,
                                              uinit, qs, cs, acc);

    combine_kernel<<<1, 64, 0, stream>>>(acc, sd0, sd1, sdq, (float*)d_out);
}

// Round 10
// 192.990 us; speedup vs baseline: 1.1645x; 1.0525x over previous
//
#include <hip/hip_runtime.h>
#include <hip/hip_bf16.h>

#define EPSF 1e-8f
#define NN 50000
#define DD 128
#define BB 64
#define LL 512
#define PP0 200000
#define PP1 50000
#define SCALE 0.08838834764831845f  // 1/sqrt(128)

#define E0B 1024
#define E1B 640

typedef float f4v __attribute__((ext_vector_type(4)));
typedef float f2v __attribute__((ext_vector_type(2)));
typedef short s8v __attribute__((ext_vector_type(8)));
typedef short s4v __attribute__((ext_vector_type(4)));

__device__ __forceinline__ float logsigf(float x) {
    float s = 1.f / (1.f + __expf(-x));
    return __logf(s + EPSF);
}

__device__ __forceinline__ float red64(float v) {
    #pragma unroll
    for (int m = 32; m >= 1; m >>= 1) v += __shfl_xor(v, m, 64);
    return v;
}
__device__ __forceinline__ float red16(float v) {
    #pragma unroll
    for (int m = 8; m >= 1; m >>= 1) v += __shfl_xor(v, m, 64);
    return v;
}
__device__ __forceinline__ float red8(float v) {
    #pragma unroll
    for (int m = 4; m >= 1; m >>= 1) v += __shfl_xor(v, m, 64);
    return v;
}

__device__ __forceinline__ void block_atomic_sum(float local, float* dst) {
    local = red64(local);
    __shared__ float w4[4];
    if ((threadIdx.x & 63) == 0) w4[threadIdx.x >> 6] = local;
    __syncthreads();
    if (threadIdx.x == 0) atomicAdd(dst, w4[0] + w4[1] + w4[2] + w4[3]);
}

// float -> bf16 bits (round-to-nearest-even)
__device__ __forceinline__ unsigned short f2bf(float f) {
    unsigned u = __float_as_uint(f);
    unsigned r = (u + 0x7fffu + ((u >> 16) & 1u)) >> 16;
    return (unsigned short)r;
}
__device__ __forceinline__ float bf2f(unsigned short u) {
    return __uint_as_float(((unsigned)u) << 16);
}

__device__ __forceinline__ float dot8bf(s8v a, s8v b) {
    float s = 0.f;
    #pragma unroll
    for (int j = 0; j < 8; j++)
        s += bf2f((unsigned short)a[j]) * bf2f((unsigned short)b[j]);
    return s;
}

// fp8 e4m3 16-element dot via HW pk converts
__device__ __forceinline__ float dotf8(int4 A, int4 B) {
    int ae[4] = {A.x, A.y, A.z, A.w};
    int be[4] = {B.x, B.y, B.z, B.w};
    float s = 0.f;
    #pragma unroll
    for (int j = 0; j < 4; j++) {
        f2v a0 = __builtin_amdgcn_cvt_pk_f32_fp8(ae[j], false);
        f2v a1 = __builtin_amdgcn_cvt_pk_f32_fp8(ae[j], true);
        f2v b0 = __builtin_amdgcn_cvt_pk_f32_fp8(be[j], false);
        f2v b1 = __builtin_amdgcn_cvt_pk_f32_fp8(be[j], true);
        s += a0.x * b0.x + a0.y * b0.y + a1.x * b1.x + a1.y * b1.y;
    }
    return s;
}

// ---------------- one-shot convert: emb -> bf16 table + fp8 table -----------
// also zeroes the accumulator slots (replaces the memset dispatch)
__global__ __launch_bounds__(256) void cvt_emb_kernel(
    const float* __restrict__ emb, unsigned short* __restrict__ emb16,
    unsigned char* __restrict__ emb8, float* __restrict__ acc)
{
    if (blockIdx.x == 0 && threadIdx.x < 16) acc[threadIdx.x] = 0.f;
    int stride = gridDim.x * 256 * 8;
    for (int i = (blockIdx.x * 256 + threadIdx.x) * 8; i < NN * DD; i += stride) {
        float4 a = *(const float4*)&emb[i];
        float4 b = *(const float4*)&emb[i + 4];
        s8v o;
        o[0] = (short)f2bf(a.x); o[1] = (short)f2bf(a.y);
        o[2] = (short)f2bf(a.z); o[3] = (short)f2bf(a.w);
        o[4] = (short)f2bf(b.x); o[5] = (short)f2bf(b.y);
        o[6] = (short)f2bf(b.z); o[7] = (short)f2bf(b.w);
        *(s8v*)&emb16[i] = o;
        int lo = __builtin_amdgcn_cvt_pk_fp8_f32(a.x, a.y, 0, false);
        lo = __builtin_amdgcn_cvt_pk_fp8_f32(a.z, a.w, lo, true);
        int hi = __builtin_amdgcn_cvt_pk_fp8_f32(b.x, b.y, 0, false);
        hi = __builtin_amdgcn_cvt_pk_fp8_f32(b.z, b.w, hi, true);
        *(int2*)&emb8[i] = make_int2(lo, hi);
    }
}

// ---------------- Edge tasks on the fp8 table (128 B rows) ------------------
__global__ __launch_bounds__(256) void edges_kernel(
    const unsigned char* __restrict__ emb8, const int* __restrict__ pos,
    const int* __restrict__ neg, const int* __restrict__ pos1,
    const int* __restrict__ neg1, float* __restrict__ acc)
{
    int sub = threadIdx.x & 7;
    if (blockIdx.x < E0B) {
        int g0 = (blockIdx.x * 256 + threadIdx.x) >> 3;
        const int ng = E0B * 32;
        float local = 0.f;
        for (int grp = g0; grp < 2 * PP0; grp += ng) {
            bool isneg = grp >= PP0;
            const int* e = isneg ? (neg + 2 * (grp - PP0)) : (pos + 2 * grp);
            int h = e[0], t = e[1];
            int4 a = ((const int4*)(emb8 + (size_t)h * DD))[sub];
            int4 b = ((const int4*)(emb8 + (size_t)t * DD))[sub];
            float d = red8(dotf8(a, b));
            if (sub == 0) local += logsigf(isneg ? -d : d);
        }
        block_atomic_sum(local, acc);
    } else {
        int g0 = ((blockIdx.x - E0B) * 256 + threadIdx.x) >> 3;
        const int ng = E1B * 32;
        float local = 0.f;
        for (int i = g0; i < PP1; i += ng) {
            int ph = pos1[2 * i], pt = pos1[2 * i + 1];
            int4 vph = ((const int4*)(emb8 + (size_t)ph * DD))[sub];
            int4 vpt = ((const int4*)(emb8 + (size_t)pt * DD))[sub];
            float ps = red8(dotf8(vph, vpt));
            #pragma unroll
            for (int mloop = 0; mloop < 4; mloop++) {
                int g = mloop * PP1 + i;
                int nh = neg1[2 * g], nt = neg1[2 * g + 1];
                int4 vnh = ((const int4*)(emb8 + (size_t)nh * DD))[sub];
                int4 vnt = ((const int4*)(emb8 + (size_t)nt * DD))[sub];
                float sh = red8(dotf8(vnh, vpt));
                float st = red8(dotf8(vph, vnt));
                if (sub == 0) local += logsigf(ps - sh) + logsigf(ps - st);
            }
        }
        block_atomic_sum(local, acc + 1);
    }
}

// ---------------- QKV projection, bf16 MFMA, inline W conversion ------------
__global__ __launch_bounds__(256) void proj_kernel(
    const unsigned short* __restrict__ emb16, const float* __restrict__ Wrep,
    const float* __restrict__ Wq, const float* __restrict__ Wk,
    const float* __restrict__ Wv, const int* __restrict__ qseq,
    const int* __restrict__ cseq, unsigned short* __restrict__ QT16,
    unsigned short* __restrict__ KT16, unsigned short* __restrict__ VT16T)
{
    int b = blockIdx.y;
    int t0 = blockIdx.x * 64;
    __shared__ unsigned short Itok[64 * 136];
    __shared__ unsigned short Wl[128 * 136];   // also V^T[r][t] stride 72 in epilogue
    __shared__ int qs[64];
    __shared__ int cs[64];
    int tid = threadIdx.x;
    if (tid < 64) {
        qs[tid] = qseq[b * LL + t0 + tid];
        cs[tid] = cseq[b * LL + t0 + tid];
    }
    __syncthreads();
    {   // stage I[t][d] = emb[qs[t]][d] + Wrep[d][cs[t]] as bf16
        int t = tid >> 2, d0 = (tid & 3) * 32;
        const unsigned short* er = emb16 + (size_t)qs[t] * DD + d0;
        int c = cs[t];
        #pragma unroll
        for (int e = 0; e < 32; e += 8) {
            s8v raw = *(const s8v*)&er[e];
            s8v o;
            #pragma unroll
            for (int j = 0; j < 8; j++) {
                float f = bf2f((unsigned short)raw[j]) + Wrep[(d0 + e + j) * 2 + c];
                o[j] = (short)f2bf(f);
            }
            *(s8v*)&Itok[t * 136 + d0 + e] = o;
        }
    }
    int w = tid >> 6, lane = tid & 63, n = lane & 15, quad = lane >> 4;

    for (int w3 = 0; w3 < 3; w3++) {
        const float* Wsel = (w3 == 0) ? Wq : (w3 == 1) ? Wk : Wv;
        __syncthreads();
        {   // stage W[w3]: fp32 global -> bf16 LDS
            const float* src = Wsel + (tid >> 1) * DD + (tid & 1) * 64;
            unsigned short* dst = &Wl[(tid >> 1) * 136 + (tid & 1) * 64];
            #pragma unroll
            for (int e = 0; e < 64; e += 8) {
                float4 x = *(const float4*)&src[e];
                float4 y = *(const float4*)&src[e + 4];
                s8v o;
                o[0] = (short)f2bf(x.x); o[1] = (short)f2bf(x.y);
                o[2] = (short)f2bf(x.z); o[3] = (short)f2bf(x.w);
                o[4] = (short)f2bf(y.x); o[5] = (short)f2bf(y.y);
                o[6] = (short)f2bf(y.z); o[7] = (short)f2bf(y.w);
                *(s8v*)&dst[e] = o;
            }
        }
        __syncthreads();
        f4v a2[2][4];
        #pragma unroll
        for (int mt = 0; mt < 2; mt++)
            #pragma unroll
            for (int nt = 0; nt < 4; nt++) a2[mt][nt] = (f4v){0.f, 0.f, 0.f, 0.f};
        #pragma unroll
        for (int c = 0; c < 4; c++) {
            s8v af0 = *(const s8v*)&Wl[(w * 32 + n) * 136 + c * 32 + quad * 8];
            s8v af1 = *(const s8v*)&Wl[(w * 32 + 16 + n) * 136 + c * 32 + quad * 8];
            #pragma unroll
            for (int nt = 0; nt < 4; nt++) {
                s8v bf = *(const s8v*)&Itok[(nt * 16 + n) * 136 + c * 32 + quad * 8];
                a2[0][nt] = __builtin_amdgcn_mfma_f32_16x16x32_bf16(af0, bf, a2[0][nt], 0, 0, 0);
                a2[1][nt] = __builtin_amdgcn_mfma_f32_16x16x32_bf16(af1, bf, a2[1][nt], 0, 0, 0);
            }
        }
        if (w3 < 2) {
            unsigned short* OUT = (w3 == 0) ? QT16 : KT16;
            #pragma unroll
            for (int mt = 0; mt < 2; mt++)
                #pragma unroll
                for (int nt = 0; nt < 4; nt++) {
                    int t = t0 + nt * 16 + n;
                    int r = w * 32 + mt * 16 + quad * 4;
                    s4v o;
                    #pragma unroll
                    for (int rr = 0; rr < 4; rr++) o[rr] = (short)f2bf(a2[mt][nt][rr]);
                    *(s4v*)&OUT[((size_t)(b * LL) + t) * DD + r] = o;
                }
        } else {
            __syncthreads();
            #pragma unroll
            for (int mt = 0; mt < 2; mt++)
                #pragma unroll
                for (int nt = 0; nt < 4; nt++) {
                    int tl = nt * 16 + n;
                    int r = w * 32 + mt * 16 + quad * 4;
                    #pragma unroll
                    for (int rr = 0; rr < 4; rr++)
                        Wl[(r + rr) * 72 + tl] = f2bf(a2[mt][nt][rr]);
                }
            __syncthreads();
            int row = tid >> 1, half = tid & 1;
            unsigned short* gdst = VT16T + ((size_t)b * DD + row) * LL + t0 + half * 32;
            const unsigned short* lsrc = &Wl[row * 72 + half * 32];
            #pragma unroll
            for (int e = 0; e < 32; e += 8)
                *(s8v*)&gdst[e] = *(const s8v*)&lsrc[e];
        }
    }
}

// ---------------- Flash attention + head + pred, fully fused ----------------
// LDS union (52 KB, 3 blocks/CU):
//   kt-loop : K[64*136] | Vt[128*72] | P[64*72]
//   epilogue: Bv[64*136] | Hl[64*136] | O[64*136]
__global__ __launch_bounds__(256) void attn_head_kernel(
    const unsigned short* __restrict__ QT16, const unsigned short* __restrict__ KT16,
    const unsigned short* __restrict__ VT16T, const float* __restrict__ Hd,
    const unsigned short* __restrict__ emb16, const float* __restrict__ uinit,
    const int* __restrict__ qseq, const int* __restrict__ cseq,
    float* __restrict__ acc)
{
    __shared__ unsigned short U[26112];
    unsigned short* K_lds  = U;            // 64*136 = 8704
    unsigned short* Vt_lds = U + 8704;     // 128*72 = 9216
    unsigned short* P_lds  = U + 17920;    // 64*72  = 4608 (end 22528)
    unsigned short* Bv_lds = U;            // 64*136
    unsigned short* Hl     = U + 8704;     // 64*136 (end 17408)
    unsigned short* O_lds  = U + 17408;    // 64*136 (end 26112)

    int id = blockIdx.x;
    int r0 = id & 255;
    int b = r0 & 63;
    int qt = (id >> 8) ? (7 - (r0 >> 6)) : (r0 >> 6);

    int tid = threadIdx.x;
    int w = tid >> 6;
    int lane = tid & 63;
    int n = lane & 15;
    int quad = lane >> 4;
    int gj = qt * 64 + w * 16 + n;

    s8v qfrag[4];
    {
        const unsigned short* qrow = QT16 + ((size_t)(b * LL) + gj) * DD;
        #pragma unroll
        for (int c = 0; c < 4; c++)
            qfrag[c] = *(const s8v*)&qrow[c * 32 + quad * 8];
    }

    f4v oacc[8];
    #pragma unroll
    for (int dt = 0; dt < 8; dt++) oacc[dt] = (f4v){0.f, 0.f, 0.f, 0.f};
    float m_run = -INFINITY, l_run = 0.f;

    s8v kreg[4], vreg[4];
    #pragma unroll
    for (int rep = 0; rep < 4; rep++) {
        int idx = rep * 2048 + tid * 8;
        int ki = idx >> 7, kd = idx & 127;
        kreg[rep] = *(const s8v*)&KT16[((size_t)(b * LL) + ki) * DD + kd];
        int vr = idx >> 6, vc = idx & 63;
        vreg[rep] = *(const s8v*)&VT16T[((size_t)b * DD + vr) * LL + vc];
    }

    for (int kt = 0; kt <= qt; ++kt) {
        __syncthreads();
        #pragma unroll
        for (int rep = 0; rep < 4; rep++) {
            int idx = rep * 2048 + tid * 8;
            int ki = idx >> 7, kd = idx & 127;
            *(s8v*)&K_lds[ki * 136 + kd] = kreg[rep];
            int vr = idx >> 6, vc = idx & 63;
            *(s8v*)&Vt_lds[vr * 72 + vc] = vreg[rep];
        }
        __syncthreads();
        if (kt < qt) {
            #pragma unroll
            for (int rep = 0; rep < 4; rep++) {
                int idx = rep * 2048 + tid * 8;
                int ki = idx >> 7, kd = idx & 127;
                kreg[rep] = *(const s8v*)&KT16[((size_t)(b * LL) + (kt + 1) * 64 + ki) * DD + kd];
                int vr = idx >> 6, vc = idx & 63;
                vreg[rep] = *(const s8v*)&VT16T[((size_t)b * DD + vr) * LL + (kt + 1) * 64 + vc];
            }
        }

        f4v sacc[4];
        #pragma unroll
        for (int mt = 0; mt < 4; mt++) sacc[mt] = (f4v){0.f, 0.f, 0.f, 0.f};
        #pragma unroll
        for (int c = 0; c < 4; c++) {
            #pragma unroll
            for (int mt = 0; mt < 4; mt++) {
                s8v af = *(const s8v*)&K_lds[(mt * 16 + n) * 136 + c * 32 + quad * 8];
                sacc[mt] = __builtin_amdgcn_mfma_f32_16x16x32_bf16(af, qfrag[c], sacc[mt], 0, 0, 0);
            }
        }

        bool diag = (kt == qt);
        float mloc = -INFINITY;
        #pragma unroll
        for (int mt = 0; mt < 4; mt++) {
            #pragma unroll
            for (int rr = 0; rr < 4; rr++) {
                float s = sacc[mt][rr] * SCALE;
                if (diag && (kt * 64 + mt * 16 + quad * 4 + rr) > gj) s = -INFINITY;
                sacc[mt][rr] = s;
                mloc = fmaxf(mloc, s);
            }
        }
        mloc = fmaxf(mloc, __shfl_xor(mloc, 16));
        mloc = fmaxf(mloc, __shfl_xor(mloc, 32));
        float mnew = fmaxf(m_run, mloc);
        float alpha = __expf(m_run - mnew);
        m_run = mnew;

        float rsum = 0.f;
        #pragma unroll
        for (int mt = 0; mt < 4; mt++) {
            s4v pp;
            #pragma unroll
            for (int rr = 0; rr < 4; rr++) {
                float p = __expf(sacc[mt][rr] - mnew);
                rsum += p;
                pp[rr] = (short)f2bf(p);
            }
            *(s4v*)&P_lds[(w * 16 + n) * 72 + mt * 16 + quad * 4] = pp;
        }
        rsum += __shfl_xor(rsum, 16);
        rsum += __shfl_xor(rsum, 32);
        l_run = l_run * alpha + rsum;

        #pragma unroll
        for (int rr = 0; rr < 4; rr++) {
            float a_r = __shfl(alpha, quad * 4 + rr);
            #pragma unroll
            for (int dt = 0; dt < 8; dt++) oacc[dt][rr] *= a_r;
        }

        #pragma unroll
        for (int cc = 0; cc < 2; cc++) {
            s8v pf = *(const s8v*)&P_lds[(w * 16 + n) * 72 + cc * 32 + quad * 8];
            #pragma unroll
            for (int dt = 0; dt < 8; dt++) {
                s8v vf = *(const s8v*)&Vt_lds[(dt * 16 + n) * 72 + cc * 32 + quad * 8];
                oacc[dt] = __builtin_amdgcn_mfma_f32_16x16x32_bf16(pf, vf, oacc[dt], 0, 0, 0);
            }
        }
    }

    // ---- epilogue: Bv -> LDS (bf16, /l), O = Head_agg @ Bv, pred loss ----
    __syncthreads();
    {
        float linv = 1.f / l_run;
        #pragma unroll
        for (int rr = 0; rr < 4; rr++) {
            float li = __shfl(linv, quad * 4 + rr);
            int tl = w * 16 + quad * 4 + rr;
            #pragma unroll
            for (int dt = 0; dt < 8; dt++)
                Bv_lds[tl * 136 + dt * 16 + n] = f2bf(oacc[dt][rr] * li);
        }
    }

    #pragma unroll
    for (int pass = 0; pass < 2; pass++) {
        __syncthreads();
        {   // stage H rows [pass*64, +64) fp32 -> bf16
            int r = tid >> 2, d0 = (tid & 3) * 32;
            const float* src = Hd + (size_t)(pass * 64 + r) * DD + d0;
            #pragma unroll
            for (int e = 0; e < 32; e += 8) {
                float4 x = *(const float4*)&src[e];
                float4 y = *(const float4*)&src[e + 4];
                s8v o;
                o[0] = (short)f2bf(x.x); o[1] = (short)f2bf(x.y);
                o[2] = (short)f2bf(x.z); o[3] = (short)f2bf(x.w);
                o[4] = (short)f2bf(y.x); o[5] = (short)f2bf(y.y);
                o[6] = (short)f2bf(y.z); o[7] = (short)f2bf(y.w);
                *(s8v*)&Hl[r * 136 + d0 + e] = o;
            }
        }
        __syncthreads();
        f4v o2[4];
        #pragma unroll
        for (int nt = 0; nt < 4; nt++) o2[nt] = (f4v){0.f, 0.f, 0.f, 0.f};
        #pragma unroll
        for (int c = 0; c < 4; c++) {
            s8v af = *(const s8v*)&Hl[(w * 16 + n) * 136 + c * 32 + quad * 8];
            #pragma unroll
            for (int nt = 0; nt < 4; nt++) {
                s8v bf = *(const s8v*)&Bv_lds[(nt * 16 + n) * 136 + c * 32 + quad * 8];
                o2[nt] = __builtin_amdgcn_mfma_f32_16x16x32_bf16(af, bf, o2[nt], 0, 0, 0);
            }
        }
        int rbase = pass * 64 + w * 16 + quad * 4;
        #pragma unroll
        for (int nt = 0; nt < 4; nt++) {
            int tl = nt * 16 + n;
            #pragma unroll
            for (int rr = 0; rr < 4; rr++)
                O_lds[tl * 136 + rbase + rr] = f2bf(o2[nt][rr]);
        }
    }
    __syncthreads();

    // pred: term t = qt*64 + tl + 1 uses u = O[tl]; 16 groups x 16 lanes
    int g2 = tid >> 4, sub = tid & 15;
    float local = 0.f;
    #pragma unroll
    for (int tt = 0; tt < 4; tt++) {
        int tl = g2 * 4 + tt;
        int t = qt * 64 + tl + 1;
        if (t < LL) {
            s8v uv = *(const s8v*)&O_lds[tl * 136 + sub * 8];
            int qi = qseq[b * LL + t];
            s8v ev = *(const s8v*)&emb16[(size_t)qi * DD + sub * 8];
            float s = red16(dot8bf(uv, ev));
            if (sub == 0) {
                float c = (float)cseq[b * LL + t];
                float pred = 1.f / (1.f + __expf(-s));
                local += c * __logf(pred + EPSF) + (1.f - c) * __logf(1.f - pred + EPSF);
            }
        }
    }
    if (qt == 0 && g2 == 0) {   // t = 0 term with user_init (fp32)
        int qi = qseq[b * LL];
        s8v ev = *(const s8v*)&emb16[(size_t)qi * DD + sub * 8];
        float4 u0 = *(const float4*)&uinit[sub * 8];
        float4 u1 = *(const float4*)&uinit[sub * 8 + 4];
        float s = u0.x * bf2f((unsigned short)ev[0]) + u0.y * bf2f((unsigned short)ev[1])
                + u0.z * bf2f((unsigned short)ev[2]) + u0.w * bf2f((unsigned short)ev[3])
                + u1.x * bf2f((unsigned short)ev[4]) + u1.y * bf2f((unsigned short)ev[5])
                + u1.z * bf2f((unsigned short)ev[6]) + u1.w * bf2f((unsigned short)ev[7]);
        s = red16(s);
        if (sub == 0) {
            float c = (float)cseq[b * LL];
            float pred = 1.f / (1.f + __expf(-s));
            local += c * __logf(pred + EPSF) + (1.f - c) * __logf(1.f - pred + EPSF);
        }
    }
    block_atomic_sum(local, acc + 2);
}

// ---------------- final combine ---------------------------------------------
__global__ void combine_kernel(
    const float* __restrict__ acc, const float* __restrict__ sd0p,
    const float* __restrict__ sd1p, const float* __restrict__ sdqp,
    float* __restrict__ out)
{
    if (threadIdx.x == 0 && blockIdx.x == 0) {
        float l0 = -acc[0], l1 = -acc[1], ls = -acc[2];
        float s0 = *sd0p, s1 = *sd1p, ss = *sdqp;
        float tf = l0 / (s0 * s0 + EPSF) + 400000.f * logf(s0 + EPSF)
                 + l1 / (s1 * s1 + EPSF) + 400000.f * logf(s1 + EPSF)
                 + ls / (ss * ss + EPSF) + 512.f * logf(ss + EPSF);
        out[0] = tf;
    }
}

extern "C" void kernel_launch(void* const* d_in, const int* in_sizes, int n_in,
                              void* d_out, int out_size, void* d_ws, size_t ws_size,
                              hipStream_t stream) {
    const float* emb   = (const float*)d_in[0];
    const float* Wrep  = (const float*)d_in[1];
    const float* Wq    = (const float*)d_in[2];
    const float* Wk    = (const float*)d_in[3];
    const float* Wv    = (const float*)d_in[4];
    const float* Hd    = (const float*)d_in[5];
    const float* uinit = (const float*)d_in[6];
    const float* sd0   = (const float*)d_in[7];
    const float* sd1   = (const float*)d_in[8];
    const float* sdq   = (const float*)d_in[9];
    const int* pe0 = (const int*)d_in[10];
    const int* ne0 = (const int*)d_in[11];
    const int* pe1 = (const int*)d_in[12];
    const int* ne1 = (const int*)d_in[13];
    const int* qs  = (const int*)d_in[14];
    const int* cs  = (const int*)d_in[15];

    const size_t SZ = (size_t)BB * LL * DD;   // 4,194,304
    char* base = (char*)d_ws;
    float* acc = (float*)base;                                  // 256 B
    unsigned short* emb16 = (unsigned short*)(base + 256);      // 12.8 MB
    unsigned char* emb8   = (unsigned char*)(emb16 + (size_t)NN * DD);  // 6.4 MB
    unsigned short* QT16  = (unsigned short*)(emb8 + (size_t)NN * DD);
    unsigned short* KT16  = QT16 + SZ;
    unsigned short* VT16T = KT16 + SZ;                          // [b][128][512]

    cvt_emb_kernel<<<1024, 256, 0, stream>>>(emb, emb16, emb8, acc);

    edges_kernel<<<E0B + E1B, 256, 0, stream>>>(emb8, pe0, ne0, pe1, ne1, acc);

    proj_kernel<<<dim3(8, 64), 256, 0, stream>>>(emb16, Wrep, Wq, Wk, Wv,
                                                 qs, cs, QT16, KT16, VT16T);
    attn_head_kernel<<<512, 256, 0, stream>>>(QT16, KT16, VT16T, Hd, emb16,
                                              uinit, qs, cs, acc);

    combine_kernel<<<1, 64, 0, stream>>>(acc, sd0, sd1, sdq, (float*)d_out);
}

// Round 12
// 191.646 us; speedup vs baseline: 1.1727x; 1.0070x over previous
//
#include <hip/hip_runtime.h>
#include <hip/hip_bf16.h>

#define EPSF 1e-8f
#define NN 50000
#define DD 128
#define BB 64
#define LL 512
#define PP0 200000
#define PP1 50000
#define SCALE 0.08838834764831845f  // 1/sqrt(128)

#define E0B 1024
#define E1B 640

typedef float f4v __attribute__((ext_vector_type(4)));
typedef float f2v __attribute__((ext_vector_type(2)));
typedef short s8v __attribute__((ext_vector_type(8)));
typedef short s4v __attribute__((ext_vector_type(4)));

__device__ __forceinline__ float logsigf(float x) {
    float s = 1.f / (1.f + __expf(-x));
    return __logf(s + EPSF);
}

__device__ __forceinline__ float red64(float v) {
    #pragma unroll
    for (int m = 32; m >= 1; m >>= 1) v += __shfl_xor(v, m, 64);
    return v;
}
__device__ __forceinline__ float red16(float v) {
    #pragma unroll
    for (int m = 8; m >= 1; m >>= 1) v += __shfl_xor(v, m, 64);
    return v;
}
__device__ __forceinline__ float red8(float v) {
    #pragma unroll
    for (int m = 4; m >= 1; m >>= 1) v += __shfl_xor(v, m, 64);
    return v;
}

__device__ __forceinline__ void block_atomic_sum(float local, float* dst) {
    local = red64(local);
    __shared__ float w4[4];
    if ((threadIdx.x & 63) == 0) w4[threadIdx.x >> 6] = local;
    __syncthreads();
    if (threadIdx.x == 0) atomicAdd(dst, w4[0] + w4[1] + w4[2] + w4[3]);
}

// float -> bf16 bits (round-to-nearest-even)
__device__ __forceinline__ unsigned short f2bf(float f) {
    unsigned u = __float_as_uint(f);
    unsigned r = (u + 0x7fffu + ((u >> 16) & 1u)) >> 16;
    return (unsigned short)r;
}
__device__ __forceinline__ float bf2f(unsigned short u) {
    return __uint_as_float(((unsigned)u) << 16);
}

__device__ __forceinline__ float dot8bf(s8v a, s8v b) {
    float s = 0.f;
    #pragma unroll
    for (int j = 0; j < 8; j++)
        s += bf2f((unsigned short)a[j]) * bf2f((unsigned short)b[j]);
    return s;
}

// fp8 e4m3 16-element dot via HW pk converts
__device__ __forceinline__ float dotf8(int4 A, int4 B) {
    int ae[4] = {A.x, A.y, A.z, A.w};
    int be[4] = {B.x, B.y, B.z, B.w};
    float s = 0.f;
    #pragma unroll
    for (int j = 0; j < 4; j++) {
        f2v a0 = __builtin_amdgcn_cvt_pk_f32_fp8(ae[j], false);
        f2v a1 = __builtin_amdgcn_cvt_pk_f32_fp8(ae[j], true);
        f2v b0 = __builtin_amdgcn_cvt_pk_f32_fp8(be[j], false);
        f2v b1 = __builtin_amdgcn_cvt_pk_f32_fp8(be[j], true);
        s += a0.x * b0.x + a0.y * b0.y + a1.x * b1.x + a1.y * b1.y;
    }
    return s;
}

// pack 4 fp32 -> 4 fp8 (e4m3) in one uint
__device__ __forceinline__ unsigned pk4fp8(float v0, float v1, float v2, float v3) {
    unsigned u = __builtin_amdgcn_cvt_pk_fp8_f32(v0, v1, 0, false);
    u = __builtin_amdgcn_cvt_pk_fp8_f32(v2, v3, u, true);
    return u;
}

// ---------------- one-shot convert: emb -> bf16 table + fp8 table -----------
// also zeroes the accumulator slots (replaces the memset dispatch)
__global__ __launch_bounds__(256) void cvt_emb_kernel(
    const float* __restrict__ emb, unsigned short* __restrict__ emb16,
    unsigned char* __restrict__ emb8, float* __restrict__ acc)
{
    if (blockIdx.x == 0 && threadIdx.x < 16) acc[threadIdx.x] = 0.f;
    int stride = gridDim.x * 256 * 8;
    for (int i = (blockIdx.x * 256 + threadIdx.x) * 8; i < NN * DD; i += stride) {
        float4 a = *(const float4*)&emb[i];
        float4 b = *(const float4*)&emb[i + 4];
        s8v o;
        o[0] = (short)f2bf(a.x); o[1] = (short)f2bf(a.y);
        o[2] = (short)f2bf(a.z); o[3] = (short)f2bf(a.w);
        o[4] = (short)f2bf(b.x); o[5] = (short)f2bf(b.y);
        o[6] = (short)f2bf(b.z); o[7] = (short)f2bf(b.w);
        *(s8v*)&emb16[i] = o;
        *(uint2*)&emb8[i] = make_uint2(pk4fp8(a.x, a.y, a.z, a.w),
                                       pk4fp8(b.x, b.y, b.z, b.w));
    }
}

// ---------------- Edge tasks on the fp8 table (128 B rows) ------------------
__global__ __launch_bounds__(256) void edges_kernel(
    const unsigned char* __restrict__ emb8, const int* __restrict__ pos,
    const int* __restrict__ neg, const int* __restrict__ pos1,
    const int* __restrict__ neg1, float* __restrict__ acc)
{
    int sub = threadIdx.x & 7;
    if (blockIdx.x < E0B) {
        int g0 = (blockIdx.x * 256 + threadIdx.x) >> 3;
        const int ng = E0B * 32;
        float local = 0.f;
        for (int grp = g0; grp < 2 * PP0; grp += ng) {
            bool isneg = grp >= PP0;
            const int* e = isneg ? (neg + 2 * (grp - PP0)) : (pos + 2 * grp);
            int h = e[0], t = e[1];
            int4 a = ((const int4*)(emb8 + (size_t)h * DD))[sub];
            int4 b = ((const int4*)(emb8 + (size_t)t * DD))[sub];
            float d = red8(dotf8(a, b));
            if (sub == 0) local += logsigf(isneg ? -d : d);
        }
        block_atomic_sum(local, acc);
    } else {
        int g0 = ((blockIdx.x - E0B) * 256 + threadIdx.x) >> 3;
        const int ng = E1B * 32;
        float local = 0.f;
        for (int i = g0; i < PP1; i += ng) {
            int ph = pos1[2 * i], pt = pos1[2 * i + 1];
            int4 vph = ((const int4*)(emb8 + (size_t)ph * DD))[sub];
            int4 vpt = ((const int4*)(emb8 + (size_t)pt * DD))[sub];
            float ps = red8(dotf8(vph, vpt));
            #pragma unroll
            for (int mloop = 0; mloop < 4; mloop++) {
                int g = mloop * PP1 + i;
                int nh = neg1[2 * g], nt = neg1[2 * g + 1];
                int4 vnh = ((const int4*)(emb8 + (size_t)nh * DD))[sub];
                int4 vnt = ((const int4*)(emb8 + (size_t)nt * DD))[sub];
                float sh = red8(dotf8(vnh, vpt));
                float st = red8(dotf8(vph, vnt));
                if (sub == 0) local += logsigf(ps - sh) + logsigf(ps - st);
            }
        }
        block_atomic_sum(local, acc + 1);
    }
}

// ---------------- QKV projection, bf16 MFMA, inline W conversion ------------
__global__ __launch_bounds__(256) void proj_kernel(
    const unsigned short* __restrict__ emb16, const float* __restrict__ Wrep,
    const float* __restrict__ Wq, const float* __restrict__ Wk,
    const float* __restrict__ Wv, const int* __restrict__ qseq,
    const int* __restrict__ cseq, unsigned short* __restrict__ QT16,
    unsigned short* __restrict__ KT16, unsigned short* __restrict__ VT16T)
{
    int b = blockIdx.y;
    int t0 = blockIdx.x * 64;
    __shared__ unsigned short Itok[64 * 136];
    __shared__ unsigned short Wl[128 * 136];   // also V^T[r][t] stride 72 in epilogue
    __shared__ int qs[64];
    __shared__ int cs[64];
    int tid = threadIdx.x;
    if (tid < 64) {
        qs[tid] = qseq[b * LL + t0 + tid];
        cs[tid] = cseq[b * LL + t0 + tid];
    }
    __syncthreads();
    {   // stage I[t][d] = emb[qs[t]][d] + Wrep[d][cs[t]] as bf16
        int t = tid >> 2, d0 = (tid & 3) * 32;
        const unsigned short* er = emb16 + (size_t)qs[t] * DD + d0;
        int c = cs[t];
        #pragma unroll
        for (int e = 0; e < 32; e += 8) {
            s8v raw = *(const s8v*)&er[e];
            s8v o;
            #pragma unroll
            for (int j = 0; j < 8; j++) {
                float f = bf2f((unsigned short)raw[j]) + Wrep[(d0 + e + j) * 2 + c];
                o[j] = (short)f2bf(f);
            }
            *(s8v*)&Itok[t * 136 + d0 + e] = o;
        }
    }
    int w = tid >> 6, lane = tid & 63, n = lane & 15, quad = lane >> 4;

    for (int w3 = 0; w3 < 3; w3++) {
        const float* Wsel = (w3 == 0) ? Wq : (w3 == 1) ? Wk : Wv;
        __syncthreads();
        {   // stage W[w3]: fp32 global -> bf16 LDS
            const float* src = Wsel + (tid >> 1) * DD + (tid & 1) * 64;
            unsigned short* dst = &Wl[(tid >> 1) * 136 + (tid & 1) * 64];
            #pragma unroll
            for (int e = 0; e < 64; e += 8) {
                float4 x = *(const float4*)&src[e];
                float4 y = *(const float4*)&src[e + 4];
                s8v o;
                o[0] = (short)f2bf(x.x); o[1] = (short)f2bf(x.y);
                o[2] = (short)f2bf(x.z); o[3] = (short)f2bf(x.w);
                o[4] = (short)f2bf(y.x); o[5] = (short)f2bf(y.y);
                o[6] = (short)f2bf(y.z); o[7] = (short)f2bf(y.w);
                *(s8v*)&dst[e] = o;
            }
        }
        __syncthreads();
        f4v a2[2][4];
        #pragma unroll
        for (int mt = 0; mt < 2; mt++)
            #pragma unroll
            for (int nt = 0; nt < 4; nt++) a2[mt][nt] = (f4v){0.f, 0.f, 0.f, 0.f};
        #pragma unroll
        for (int c = 0; c < 4; c++) {
            s8v af0 = *(const s8v*)&Wl[(w * 32 + n) * 136 + c * 32 + quad * 8];
            s8v af1 = *(const s8v*)&Wl[(w * 32 + 16 + n) * 136 + c * 32 + quad * 8];
            #pragma unroll
            for (int nt = 0; nt < 4; nt++) {
                s8v bf = *(const s8v*)&Itok[(nt * 16 + n) * 136 + c * 32 + quad * 8];
                a2[0][nt] = __builtin_amdgcn_mfma_f32_16x16x32_bf16(af0, bf, a2[0][nt], 0, 0, 0);
                a2[1][nt] = __builtin_amdgcn_mfma_f32_16x16x32_bf16(af1, bf, a2[1][nt], 0, 0, 0);
            }
        }
        if (w3 < 2) {
            unsigned short* OUT = (w3 == 0) ? QT16 : KT16;
            #pragma unroll
            for (int mt = 0; mt < 2; mt++)
                #pragma unroll
                for (int nt = 0; nt < 4; nt++) {
                    int t = t0 + nt * 16 + n;
                    int r = w * 32 + mt * 16 + quad * 4;
                    s4v o;
                    #pragma unroll
                    for (int rr = 0; rr < 4; rr++) o[rr] = (short)f2bf(a2[mt][nt][rr]);
                    *(s4v*)&OUT[((size_t)(b * LL) + t) * DD + r] = o;
                }
        } else {
            __syncthreads();
            #pragma unroll
            for (int mt = 0; mt < 2; mt++)
                #pragma unroll
                for (int nt = 0; nt < 4; nt++) {
                    int tl = nt * 16 + n;
                    int r = w * 32 + mt * 16 + quad * 4;
                    #pragma unroll
                    for (int rr = 0; rr < 4; rr++)
                        Wl[(r + rr) * 72 + tl] = f2bf(a2[mt][nt][rr]);
                }
            __syncthreads();
            int row = tid >> 1, half = tid & 1;
            unsigned short* gdst = VT16T + ((size_t)b * DD + row) * LL + t0 + half * 32;
            const unsigned short* lsrc = &Wl[row * 72 + half * 32];
            #pragma unroll
            for (int e = 0; e < 32; e += 8)
                *(s8v*)&gdst[e] = *(const s8v*)&lsrc[e];
        }
    }
}

// ---------------- Flash attention + head + pred, fully fused ----------------
// LDS union (52 KB, 3 blocks/CU):
//   kt-loop : K[64*136] | Vt[128*72] | P[64*72]
//   epilogue: Bv[64*136] | Hl[64*136] | O[64*136]
__global__ __launch_bounds__(256) void attn_head_kernel(
    const unsigned short* __restrict__ QT16, const unsigned short* __restrict__ KT16,
    const unsigned short* __restrict__ VT16T, const float* __restrict__ Hd,
    const unsigned short* __restrict__ emb16, const float* __restrict__ uinit,
    const int* __restrict__ qseq, const int* __restrict__ cseq,
    float* __restrict__ acc)
{
    __shared__ unsigned short U[26112];
    unsigned short* K_lds  = U;            // 64*136 = 8704
    unsigned short* Vt_lds = U + 8704;     // 128*72 = 9216
    unsigned short* P_lds  = U + 17920;    // 64*72  = 4608 (end 22528)
    unsigned short* Bv_lds = U;            // 64*136
    unsigned short* Hl     = U + 8704;     // 64*136 (end 17408)
    unsigned short* O_lds  = U + 17408;    // 64*136 (end 26112)

    int id = blockIdx.x;
    int r0 = id & 255;
    int b = r0 & 63;
    int qt = (id >> 8) ? (7 - (r0 >> 6)) : (r0 >> 6);

    int tid = threadIdx.x;
    int w = tid >> 6;
    int lane = tid & 63;
    int n = lane & 15;
    int quad = lane >> 4;
    int gj = qt * 64 + w * 16 + n;

    s8v qfrag[4];
    {
        const unsigned short* qrow = QT16 + ((size_t)(b * LL) + gj) * DD;
        #pragma unroll
        for (int c = 0; c < 4; c++)
            qfrag[c] = *(const s8v*)&qrow[c * 32 + quad * 8];
    }

    f4v oacc[8];
    #pragma unroll
    for (int dt = 0; dt < 8; dt++) oacc[dt] = (f4v){0.f, 0.f, 0.f, 0.f};
    float m_run = -INFINITY, l_run = 0.f;

    s8v kreg[4], vreg[4];
    #pragma unroll
    for (int rep = 0; rep < 4; rep++) {
        int idx = rep * 2048 + tid * 8;
        int ki = idx >> 7, kd = idx & 127;
        kreg[rep] = *(const s8v*)&KT16[((size_t)(b * LL) + ki) * DD + kd];
        int vr = idx >> 6, vc = idx & 63;
        vreg[rep] = *(const s8v*)&VT16T[((size_t)b * DD + vr) * LL + vc];
    }

    for (int kt = 0; kt <= qt; ++kt) {
        __syncthreads();
        #pragma unroll
        for (int rep = 0; rep < 4; rep++) {
            int idx = rep * 2048 + tid * 8;
            int ki = idx >> 7, kd = idx & 127;
            *(s8v*)&K_lds[ki * 136 + kd] = kreg[rep];
            int vr = idx >> 6, vc = idx & 63;
            *(s8v*)&Vt_lds[vr * 72 + vc] = vreg[rep];
        }
        __syncthreads();
        if (kt < qt) {
            #pragma unroll
            for (int rep = 0; rep < 4; rep++) {
                int idx = rep * 2048 + tid * 8;
                int ki = idx >> 7, kd = idx & 127;
                kreg[rep] = *(const s8v*)&KT16[((size_t)(b * LL) + (kt + 1) * 64 + ki) * DD + kd];
                int vr = idx >> 6, vc = idx & 63;
                vreg[rep] = *(const s8v*)&VT16T[((size_t)b * DD + vr) * LL + (kt + 1) * 64 + vc];
            }
        }

        f4v sacc[4];
        #pragma unroll
        for (int mt = 0; mt < 4; mt++) sacc[mt] = (f4v){0.f, 0.f, 0.f, 0.f};
        #pragma unroll
        for (int c = 0; c < 4; c++) {
            #pragma unroll
            for (int mt = 0; mt < 4; mt++) {
                s8v af = *(const s8v*)&K_lds[(mt * 16 + n) * 136 + c * 32 + quad * 8];
                sacc[mt] = __builtin_amdgcn_mfma_f32_16x16x32_bf16(af, qfrag[c], sacc[mt], 0, 0, 0);
            }
        }

        bool diag = (kt == qt);
        float mloc = -INFINITY;
        #pragma unroll
        for (int mt = 0; mt < 4; mt++) {
            #pragma unroll
            for (int rr = 0; rr < 4; rr++) {
                float s = sacc[mt][rr] * SCALE;
                if (diag && (kt * 64 + mt * 16 + quad * 4 + rr) > gj) s = -INFINITY;
                sacc[mt][rr] = s;
                mloc = fmaxf(mloc, s);
            }
        }
        mloc = fmaxf(mloc, __shfl_xor(mloc, 16));
        mloc = fmaxf(mloc, __shfl_xor(mloc, 32));
        float mnew = fmaxf(m_run, mloc);
        float alpha = __expf(m_run - mnew);
        m_run = mnew;

        float rsum = 0.f;
        #pragma unroll
        for (int mt = 0; mt < 4; mt++) {
            s4v pp;
            #pragma unroll
            for (int rr = 0; rr < 4; rr++) {
                float p = __expf(sacc[mt][rr] - mnew);
                rsum += p;
                pp[rr] = (short)f2bf(p);
            }
            *(s4v*)&P_lds[(w * 16 + n) * 72 + mt * 16 + quad * 4] = pp;
        }
        rsum += __shfl_xor(rsum, 16);
        rsum += __shfl_xor(rsum, 32);
        l_run = l_run * alpha + rsum;

        #pragma unroll
        for (int rr = 0; rr < 4; rr++) {
            float a_r = __shfl(alpha, quad * 4 + rr);
            #pragma unroll
            for (int dt = 0; dt < 8; dt++) oacc[dt][rr] *= a_r;
        }

        #pragma unroll
        for (int cc = 0; cc < 2; cc++) {
            s8v pf = *(const s8v*)&P_lds[(w * 16 + n) * 72 + cc * 32 + quad * 8];
            #pragma unroll
            for (int dt = 0; dt < 8; dt++) {
                s8v vf = *(const s8v*)&Vt_lds[(dt * 16 + n) * 72 + cc * 32 + quad * 8];
                oacc[dt] = __builtin_amdgcn_mfma_f32_16x16x32_bf16(pf, vf, oacc[dt], 0, 0, 0);
            }
        }
    }

    // ---- epilogue: Bv -> LDS (bf16, /l), O = Head_agg @ Bv, pred loss ----
    __syncthreads();
    {
        float linv = 1.f / l_run;
        #pragma unroll
        for (int rr = 0; rr < 4; rr++) {
            float li = __shfl(linv, quad * 4 + rr);
            int tl = w * 16 + quad * 4 + rr;
            #pragma unroll
            for (int dt = 0; dt < 8; dt++)
                Bv_lds[tl * 136 + dt * 16 + n] = f2bf(oacc[dt][rr] * li);
        }
    }

    #pragma unroll
    for (int pass = 0; pass < 2; pass++) {
        __syncthreads();
        {   // stage H rows [pass*64, +64) fp32 -> bf16
            int r = tid >> 2, d0 = (tid & 3) * 32;
            const float* src = Hd + (size_t)(pass * 64 + r) * DD + d0;
            #pragma unroll
            for (int e = 0; e < 32; e += 8) {
                float4 x = *(const float4*)&src[e];
                float4 y = *(const float4*)&src[e + 4];
                s8v o;
                o[0] = (short)f2bf(x.x); o[1] = (short)f2bf(x.y);
                o[2] = (short)f2bf(x.z); o[3] = (short)f2bf(x.w);
                o[4] = (short)f2bf(y.x); o[5] = (short)f2bf(y.y);
                o[6] = (short)f2bf(y.z); o[7] = (short)f2bf(y.w);
                *(s8v*)&Hl[r * 136 + d0 + e] = o;
            }
        }
        __syncthreads();
        f4v o2[4];
        #pragma unroll
        for (int nt = 0; nt < 4; nt++) o2[nt] = (f4v){0.f, 0.f, 0.f, 0.f};
        #pragma unroll
        for (int c = 0; c < 4; c++) {
            s8v af = *(const s8v*)&Hl[(w * 16 + n) * 136 + c * 32 + quad * 8];
            #pragma unroll
            for (int nt = 0; nt < 4; nt++) {
                s8v bf = *(const s8v*)&Bv_lds[(nt * 16 + n) * 136 + c * 32 + quad * 8];
                o2[nt] = __builtin_amdgcn_mfma_f32_16x16x32_bf16(af, bf, o2[nt], 0, 0, 0);
            }
        }
        int rbase = pass * 64 + w * 16 + quad * 4;
        #pragma unroll
        for (int nt = 0; nt < 4; nt++) {
            int tl = nt * 16 + n;
            #pragma unroll
            for (int rr = 0; rr < 4; rr++)
                O_lds[tl * 136 + rbase + rr] = f2bf(o2[nt][rr]);
        }
    }
    __syncthreads();

    // pred: term t = qt*64 + tl + 1 uses u = O[tl]; 16 groups x 16 lanes
    int g2 = tid >> 4, sub = tid & 15;
    float local = 0.f;
    #pragma unroll
    for (int tt = 0; tt < 4; tt++) {
        int tl = g2 * 4 + tt;
        int t = qt * 64 + tl + 1;
        if (t < LL) {
            s8v uv = *(const s8v*)&O_lds[tl * 136 + sub * 8];
            int qi = qseq[b * LL + t];
            s8v ev = *(const s8v*)&emb16[(size_t)qi * DD + sub * 8];
            float s = red16(dot8bf(uv, ev));
            if (sub == 0) {
                float c = (float)cseq[b * LL + t];
                float pred = 1.f / (1.f + __expf(-s));
                local += c * __logf(pred + EPSF) + (1.f - c) * __logf(1.f - pred + EPSF);
            }
        }
    }
    if (qt == 0 && g2 == 0) {   // t = 0 term with user_init (fp32)
        int qi = qseq[b * LL];
        s8v ev = *(const s8v*)&emb16[(size_t)qi * DD + sub * 8];
        float4 u0 = *(const float4*)&uinit[sub * 8];
        float4 u1 = *(const float4*)&uinit[sub * 8 + 4];
        float s = u0.x * bf2f((unsigned short)ev[0]) + u0.y * bf2f((unsigned short)ev[1])
                + u0.z * bf2f((unsigned short)ev[2]) + u0.w * bf2f((unsigned short)ev[3])
                + u1.x * bf2f((unsigned short)ev[4]) + u1.y * bf2f((unsigned short)ev[5])
                + u1.z * bf2f((unsigned short)ev[6]) + u1.w * bf2f((unsigned short)ev[7]);
        s = red16(s);
        if (sub == 0) {
            float c = (float)cseq[b * LL];
            float pred = 1.f / (1.f + __expf(-s));
            local += c * __logf(pred + EPSF) + (1.f - c) * __logf(1.f - pred + EPSF);
        }
    }
    block_atomic_sum(local, acc + 2);
}

// ---------------- final combine ---------------------------------------------
__global__ void combine_kernel(
    const float* __restrict__ acc, const float* __restrict__ sd0p,
    const float* __restrict__ sd1p, const float* __restrict__ sdqp,
    float* __restrict__ out)
{
    if (threadIdx.x == 0 && blockIdx.x == 0) {
        float l0 = -acc[0], l1 = -acc[1], ls = -acc[2];
        float s0 = *sd0p, s1 = *sd1p, ss = *sdqp;
        float tf = l0 / (s0 * s0 + EPSF) + 400000.f * logf(s0 + EPSF)
                 + l1 / (s1 * s1 + EPSF) + 400000.f * logf(s1 + EPSF)
                 + ls / (ss * ss + EPSF) + 512.f * logf(ss + EPSF);
        out[0] = tf;
    }
}

extern "C" void kernel_launch(void* const* d_in, const int* in_sizes, int n_in,
                              void* d_out, int out_size, void* d_ws, size_t ws_size,
                              hipStream_t stream) {
    const float* emb   = (const float*)d_in[0];
    const float* Wrep  = (const float*)d_in[1];
    const float* Wq    = (const float*)d_in[2];
    const float* Wk    = (const float*)d_in[3];
    const float* Wv    = (const float*)d_in[4];
    const float* Hd    = (const float*)d_in[5];
    const float* uinit = (const float*)d_in[6];
    const float* sd0   = (const float*)d_in[7];
    const float* sd1   = (const float*)d_in[8];
    const float* sdq   = (const float*)d_in[9];
    const int* pe0 = (const int*)d_in[10];
    const int* ne0 = (const int*)d_in[11];
    const int* pe1 = (const int*)d_in[12];
    const int* ne1 = (const int*)d_in[13];
    const int* qs  = (const int*)d_in[14];
    const int* cs  = (const int*)d_in[15];

    const size_t SZ = (size_t)BB * LL * DD;   // 4,194,304
    char* base = (char*)d_ws;
    float* acc = (float*)base;                                  // 256 B
    unsigned short* emb16 = (unsigned short*)(base + 256);      // 12.8 MB
    unsigned char* emb8   = (unsigned char*)(emb16 + (size_t)NN * DD);  // 6.4 MB
    unsigned short* QT16  = (unsigned short*)(emb8 + (size_t)NN * DD);
    unsigned short* KT16  = QT16 + SZ;
    unsigned short* VT16T = KT16 + SZ;                          // [b][128][512]

    cvt_emb_kernel<<<1024, 256, 0, stream>>>(emb, emb16, emb8, acc);

    edges_kernel<<<E0B + E1B, 256, 0, stream>>>(emb8, pe0, ne0, pe1, ne1, acc);

    proj_kernel<<<dim3(8, 64), 256, 0, stream>>>(emb16, Wrep, Wq, Wk, Wv,
                                                 qs, cs, QT16, KT16, VT16T);
    attn_head_kernel<<<512, 256, 0, stream>>>(QT16, KT16, VT16T, Hd, emb16,
                                              uinit, qs, cs, acc);

    combine_kernel<<<1, 64, 0, stream>>>(acc, sd0, sd1, sdq, (float*)d_out);
}